// Round 6
// baseline (693.761 us; speedup 1.0000x reference)
//
#include <hip/hip_runtime.h>

#define Hd 256
#define Wd 256
#define HW 65536
#define C 64
#define B 8
#define M 16
#define NDEPTH 4
#define NMLP 128

typedef __attribute__((ext_vector_type(8))) __bf16 bf16x8;
typedef __attribute__((ext_vector_type(4))) float f32x4;

// lgkm-only barrier: ds visibility without draining vmcnt (in-flight prefetch).
__device__ inline void bar_lgkm() {
    asm volatile("s_waitcnt lgkmcnt(0)" ::: "memory");
    __builtin_amdgcn_s_barrier();
}

// split fp32 -> bf16 hi (RNE) + bf16 lo (RNE of residual); pack 8 -> uint4/plane.
__device__ inline void split_pack8(const float* v, uint4& hq, uint4& lq) {
    unsigned hw[4], lw[4];
#pragma unroll
    for (int i = 0; i < 4; ++i) {
        float a = v[2 * i], bb = v[2 * i + 1];
        unsigned ua = __float_as_uint(a);
        unsigned ha = (ua + 0x7fffu + ((ua >> 16) & 1u)) & 0xffff0000u;
        float ra = a - __uint_as_float(ha);
        unsigned ural = __float_as_uint(ra);
        unsigned la = (ural + 0x7fffu + ((ural >> 16) & 1u)) >> 16;
        unsigned ub = __float_as_uint(bb);
        unsigned hb = (ub + 0x7fffu + ((ub >> 16) & 1u)) & 0xffff0000u;
        float rb = bb - __uint_as_float(hb);
        unsigned urbl = __float_as_uint(rb);
        unsigned lb = (urbl + 0x7fffu + ((urbl >> 16) & 1u)) >> 16;
        hw[i] = (ha >> 16) | (hb & 0xffff0000u);
        lw[i] = la | (lb << 16);
    }
    hq = make_uint4(hw[0], hw[1], hw[2], hw[3]);
    lq = make_uint4(lw[0], lw[1], lw[2], lw[3]);
}

// scalar split
__device__ inline void split1(float s, ushort& h, ushort& l) {
    unsigned ua = __float_as_uint(s);
    unsigned ha = (ua + 0x7fffu + ((ua >> 16) & 1u)) & 0xffff0000u;
    float r = s - __uint_as_float(ha);
    unsigned ur = __float_as_uint(r);
    h = (ushort)(ha >> 16);
    l = (ushort)((ur + 0x7fffu + ((ur >> 16) & 1u)) >> 16);
}

// pack 8 zero-extended u16 -> uint4
__device__ inline uint4 pack8(const unsigned* v) {
    uint4 r;
    r.x = v[0] | (v[1] << 16);
    r.y = v[2] | (v[3] << 16);
    r.z = v[4] | (v[5] << 16);
    r.w = v[6] | (v[7] << 16);
    return r;
}

// h storage: planar split-bf16 ushort planes [b][c][y][x] (x contiguous).

// ---------------- twiddle table ----------------
__global__ void k_table(float2* __restrict__ tab) {
    int t = threadIdx.x;
    double a = (6.283185307179586476925286766559 / 256.0) * (double)t;
    tab[t] = make_float2((float)cos(a), (float)sin(a));
}

// ---------------- once: trig + pre-split cells for W-sides ----------------
__global__ void k_prep0(const float2* __restrict__ tab, const float* __restrict__ fc1w,
                        const float* __restrict__ ww, float* __restrict__ trig,
                        uint4* __restrict__ trigs_h, uint4* __restrict__ trigs_l,
                        uint4* __restrict__ wws_h, uint4* __restrict__ wws_l,
                        uint4* __restrict__ w1s_h, uint4* __restrict__ w1s_l) {
    int blk = blockIdx.x, t = threadIdx.x;
    if (blk < 32) {                    // trig[kk][x]: cos kk<16, +sin kk>=16 (fp32, fwd_x)
        int k = blk & 15;
        float2 e = tab[(k * t) & 255];
        trig[blk * 256 + t] = (blk < 16) ? e.x : e.y;
    } else if (blk < 36) {             // trigs cells [kc 4][x 256], k = trig row
        int idx = (blk - 32) * 256 + t;
        int kc = idx >> 8, x = idx & 255;
        float v[8];
#pragma unroll
        for (int j = 0; j < 8; ++j) {
            int row = kc * 8 + j;
            float2 e = tab[((row & 15) * x) & 255];
            v[j] = (row < 16) ? e.x : e.y;
        }
        uint4 hq, lq; split_pack8(v, hq, lq);
        trigs_h[idx] = hq; trigs_l[idx] = lq;
    } else if (blk < 44) {             // wws cells [(d*2+ph)*4+kc][o 64], k = i
        int idx = (blk - 36) * 256 + t;
        int o = idx & 63, kc = (idx >> 6) & 3, ph = (idx >> 8) & 1, d = idx >> 9;
        float v[8];
#pragma unroll
        for (int j = 0; j < 8; ++j)
            v[j] = ww[d * 4096 + o * 64 + ph * 32 + kc * 8 + j];
        uint4 hq, lq; split_pack8(v, hq, lq);
        wws_h[idx] = hq; wws_l[idx] = lq;
    } else {                           // w1s cells [(ph*4+kc)][m 128], k = i
        int idx = (blk - 44) * 256 + t;
        int m = idx & 127, kc = (idx >> 7) & 3, ph = idx >> 9;
        float v[8];
#pragma unroll
        for (int j = 0; j < 8; ++j)
            v[j] = fc1w[m * 64 + ph * 32 + kc * 8 + j];
        uint4 hq, lq; split_pack8(v, hq, lq);
        w1s_h[idx] = hq; w1s_l[idx] = lq;
    }
}

// ---------------- once: split-bf16 A-fragments of the y-DFT matrix ----------------
__global__ void k_prep_et(const float2* __restrict__ tab,
                          uint4* __restrict__ ETh, uint4* __restrict__ ETl) {
    int c = blockIdx.x * 256 + threadIdx.x;
    if (c >= 1024) return;
    int ph = c >> 7, kc = (c >> 5) & 3, m = c & 31;
    float v[8];
#pragma unroll
    for (int j = 0; j < 8; ++j) {
        int y = ph * 32 + kc * 8 + j;
        float2 e = tab[((m & 15) * y) & 255];
        v[j] = (m < 16) ? e.x : -e.y;
    }
    uint4 hq, lq;
    split_pack8(v, hq, lq);
    ETh[c] = hq; ETl[c] = lq;
}

// ---------------- fc0: planar split output, 8 pixels/thread ----------------
__global__ void k_fc0(const float* __restrict__ x, const float* __restrict__ w,
                      const float* __restrict__ bias,
                      ushort* __restrict__ hs_h, ushort* __restrict__ hs_l) {
    int gp = blockIdx.x * 256 + threadIdx.x;   // 65536 groups of 8 pixels
    int b = gp >> 13, pg = gp & 8191;
    int pix0 = pg * 8;
    float xv[3][8];
#pragma unroll
    for (int ch = 0; ch < 3; ++ch) {
        float4 a = *(const float4*)(x + (size_t)(b * 3 + ch) * HW + pix0);
        float4 c4 = *(const float4*)(x + (size_t)(b * 3 + ch) * HW + pix0 + 4);
        xv[ch][0] = a.x; xv[ch][1] = a.y; xv[ch][2] = a.z; xv[ch][3] = a.w;
        xv[ch][4] = c4.x; xv[ch][5] = c4.y; xv[ch][6] = c4.z; xv[ch][7] = c4.w;
    }
    for (int o = 0; o < C; ++o) {
        float w0 = w[o * 3 + 0], w1 = w[o * 3 + 1], w2 = w[o * 3 + 2], bv = bias[o];
        float v[8];
#pragma unroll
        for (int j = 0; j < 8; ++j)
            v[j] = fmaf(w0, xv[0][j], fmaf(w1, xv[1][j], fmaf(w2, xv[2][j], bv)));
        uint4 hq, lq; split_pack8(v, hq, lq);
        *(uint4*)(hs_h + (size_t)(b * 64 + o) * HW + pix0) = hq;
        *(uint4*)(hs_l + (size_t)(b * 64 + o) * HW + pix0) = lq;
    }
}

// ---------------- forward y-DFT: LDS-free split-bf16 MFMA GEMM ----------------
__global__ __launch_bounds__(256, 4)
void k_fwd_y(const ushort* __restrict__ hs_h, const ushort* __restrict__ hs_l,
             const uint4* __restrict__ ETh, const uint4* __restrict__ ETl,
             float* __restrict__ T1F) {
    int blk = blockIdx.x;                  // bc(512) * xh(2), xh fastest
    int xh = blk & 1, bc = blk >> 1;
    int x0 = xh * 128;
    int t = threadIdx.x;
    int w = t >> 6, l = t & 63;            // wave w owns x in [w*32, w*32+32)
    int lr = l & 15, lq = l >> 4;
    const ushort* pH = hs_h + (size_t)bc * HW + x0 + w * 32 + lr;
    const ushort* pL = hs_l + (size_t)bc * HW + x0 + w * 32 + lr;
    f32x4 acc[2][2];
#pragma unroll
    for (int u = 0; u < 2; ++u)
#pragma unroll
        for (int xt = 0; xt < 2; ++xt) {
            acc[u][xt][0] = 0.f; acc[u][xt][1] = 0.f;
            acc[u][xt][2] = 0.f; acc[u][xt][3] = 0.f;
        }
    unsigned h0[2][8], l0[2][8], h1[2][8], l1[2][8];
    auto loadp = [&](unsigned hv[2][8], unsigned lv[2][8], int ph) {
#pragma unroll
        for (int xt = 0; xt < 2; ++xt)
#pragma unroll
            for (int j = 0; j < 8; ++j) {
                int off = (ph * 32 + lq * 8 + j) * 256 + xt * 16;
                hv[xt][j] = pH[off];
                lv[xt][j] = pL[off];
            }
    };
    loadp(h0, l0, 0);
#pragma unroll
    for (int ph = 0; ph < 8; ++ph) {
        unsigned (*ch)[8] = (ph & 1) ? h1 : h0;
        unsigned (*cl)[8] = (ph & 1) ? l1 : l0;
        unsigned (*nh)[8] = (ph & 1) ? h0 : h1;
        unsigned (*nl)[8] = (ph & 1) ? l0 : l1;
        if (ph < 7) loadp(nh, nl, ph + 1);
        bf16x8 Ah[2], Al[2];
#pragma unroll
        for (int u = 0; u < 2; ++u) {
            int ci = ph * 128 + lq * 32 + u * 16 + lr;
            Ah[u] = __builtin_bit_cast(bf16x8, ETh[ci]);
            Al[u] = __builtin_bit_cast(bf16x8, ETl[ci]);
        }
#pragma unroll
        for (int xt = 0; xt < 2; ++xt) {
            bf16x8 Bh = __builtin_bit_cast(bf16x8, pack8(ch[xt]));
            bf16x8 Bl = __builtin_bit_cast(bf16x8, pack8(cl[xt]));
#pragma unroll
            for (int u = 0; u < 2; ++u) {
                acc[u][xt] = __builtin_amdgcn_mfma_f32_16x16x32_bf16(Ah[u], Bh, acc[u][xt], 0, 0, 0);
                acc[u][xt] = __builtin_amdgcn_mfma_f32_16x16x32_bf16(Ah[u], Bl, acc[u][xt], 0, 0, 0);
                acc[u][xt] = __builtin_amdgcn_mfma_f32_16x16x32_bf16(Al[u], Bh, acc[u][xt], 0, 0, 0);
            }
        }
    }
#pragma unroll
    for (int u = 0; u < 2; ++u)
#pragma unroll
        for (int xt = 0; xt < 2; ++xt)
#pragma unroll
            for (int g = 0; g < 4; ++g)
                T1F[(size_t)bc * 8192 + (u * 16 + lq * 4 + g) * 256 + x0 + w * 32 + xt * 16 + lr] =
                    acc[u][xt][g];
}

// ---------------- forward x-DFT (unchanged) ----------------
__global__ __launch_bounds__(256, 2)
void k_fwd_x(const float* __restrict__ T1F, const float* __restrict__ trig,
             float2* __restrict__ X) {
    __shared__ float sT[32 * 260];
    __shared__ float sG[32 * 260];
    int bc = blockIdx.x, t = threadIdx.x;
#pragma unroll
    for (int p = 0; p < 8; ++p) {
        int f = t + p * 256;
        int row = f >> 6, seg = f & 63;
        ((float4*)(sT + row * 260))[seg] = *(const float4*)(T1F + (size_t)bc * 8192 + f * 4);
        ((float4*)(sG + row * 260))[seg] = *(const float4*)(trig + row * 256 + seg * 4);
    }
    __syncthreads();
    int ky = t >> 4, kx = t & 15;
    const float* Tr = sT + ky * 260;
    const float* Ti = sT + (16 + ky) * 260;
    const float* Cs = sG + kx * 260;
    const float* Sn = sG + (16 + kx) * 260;
    float xr0 = 0.f, xi0 = 0.f, xr1 = 0.f, xi1 = 0.f;
    for (int q = 0; q < 64; q += 2) {
        float4 tr = *(const float4*)(Tr + q * 4);
        float4 ti = *(const float4*)(Ti + q * 4);
        float4 cs = *(const float4*)(Cs + q * 4);
        float4 sn = *(const float4*)(Sn + q * 4);
        xr0 = fmaf(tr.x, cs.x, xr0); xr0 = fmaf(ti.x, sn.x, xr0);
        xi0 = fmaf(ti.x, cs.x, xi0); xi0 = fmaf(-tr.x, sn.x, xi0);
        xr0 = fmaf(tr.y, cs.y, xr0); xr0 = fmaf(ti.y, sn.y, xr0);
        xi0 = fmaf(ti.y, cs.y, xi0); xi0 = fmaf(-tr.y, sn.y, xi0);
        xr0 = fmaf(tr.z, cs.z, xr0); xr0 = fmaf(ti.z, sn.z, xr0);
        xi0 = fmaf(ti.z, cs.z, xi0); xi0 = fmaf(-tr.z, sn.z, xi0);
        xr0 = fmaf(tr.w, cs.w, xr0); xr0 = fmaf(ti.w, sn.w, xr0);
        xi0 = fmaf(ti.w, cs.w, xi0); xi0 = fmaf(-tr.w, sn.w, xi0);
        float4 tr1 = *(const float4*)(Tr + q * 4 + 4);
        float4 ti1 = *(const float4*)(Ti + q * 4 + 4);
        float4 cs1 = *(const float4*)(Cs + q * 4 + 4);
        float4 sn1 = *(const float4*)(Sn + q * 4 + 4);
        xr1 = fmaf(tr1.x, cs1.x, xr1); xr1 = fmaf(ti1.x, sn1.x, xr1);
        xi1 = fmaf(ti1.x, cs1.x, xi1); xi1 = fmaf(-tr1.x, sn1.x, xi1);
        xr1 = fmaf(tr1.y, cs1.y, xr1); xr1 = fmaf(ti1.y, sn1.y, xr1);
        xi1 = fmaf(ti1.y, cs1.y, xi1); xi1 = fmaf(-tr1.y, sn1.y, xi1);
        xr1 = fmaf(tr1.z, cs1.z, xr1); xr1 = fmaf(ti1.z, sn1.z, xr1);
        xi1 = fmaf(ti1.z, cs1.z, xi1); xi1 = fmaf(-tr1.z, sn1.z, xi1);
        xr1 = fmaf(tr1.w, cs1.w, xr1); xr1 = fmaf(ti1.w, sn1.w, xr1);
        xi1 = fmaf(ti1.w, cs1.w, xi1); xi1 = fmaf(-tr1.w, sn1.w, xi1);
    }
    X[bc * 256 + t] = make_float2(xr0 + xr1, xi0 + xi1);
}

// ---------------- mode mixing (unchanged) ----------------
__global__ __launch_bounds__(256, 2)
void k_mix(const float2* __restrict__ X, const float* __restrict__ wre,
           const float* __restrict__ wim, float2* __restrict__ Y) {
    int o = blockIdx.x >> 2;
    int bq = blockIdx.x & 3;
    int m = threadIdx.x;
    int b0 = bq * 2, b1 = bq * 2 + 1;
    float yr0 = 0.f, yi0 = 0.f, yr1 = 0.f, yi1 = 0.f;
    for (int i = 0; i < C; ++i) {
        float wr = wre[(i * C + o) * 256 + m];
        float wi = wim[(i * C + o) * 256 + m];
        float2 x0 = X[(b0 * C + i) * 256 + m];
        float2 x1 = X[(b1 * C + i) * 256 + m];
        yr0 = fmaf(x0.x, wr, fmaf(-x0.y, wi, yr0));
        yi0 = fmaf(x0.x, wi, fmaf(x0.y, wr, yi0));
        yr1 = fmaf(x1.x, wr, fmaf(-x1.y, wi, yr1));
        yi1 = fmaf(x1.x, wi, fmaf(x1.y, wr, yi1));
    }
    Y[(b0 * C + o) * 256 + m] = make_float2(yr0, yi0);
    Y[(b1 * C + o) * 256 + m] = make_float2(yr1, yi1);
}

// ---------------- fused inverse-y + Gq production (unchanged) ----------------
__global__ __launch_bounds__(256, 2)
void k_invy(const float2* __restrict__ Y, const float2* __restrict__ tab,
            float* __restrict__ Gq) {
    __shared__ float2 st[256];
    int blk = blockIdx.x;              // 8b x 4pg x 16yt
    int yt = blk & 15, pg = (blk >> 4) & 3, b = blk >> 6;
    int t = threadIdx.x;
    st[t] = tab[t];
    int o = t & 63, kx = pg * 4 + (t >> 6);
    __syncthreads();
    float sc = (kx == 0 ? 1.0f : 2.0f) * (1.0f / 65536.0f);
    float yr[16], yi[16];
    const float2* yp = Y + (size_t)(b * 64 + o) * 256 + kx;
#pragma unroll
    for (int ky = 0; ky < 16; ++ky) {
        float2 v = yp[ky * 16];
        yr[ky] = v.x * sc;
        yi[ky] = v.y * sc;
    }
    int y0 = yt * 16;
    for (int yy = 0; yy < 16; ++yy) {
        int y = y0 + yy;
        float re = 0.f, im = 0.f;
#pragma unroll
        for (int ky = 0; ky < 16; ++ky) {
            float2 e = st[(ky * y) & 255];
            re = fmaf(yr[ky], e.x, re);
            re = fmaf(-yi[ky], e.y, re);
            im = fmaf(yr[ky], e.y, im);
            im = fmaf(yi[ky], e.x, im);
        }
        float* gp = Gq + (size_t)(b * 256 + y) * 32 * 64 + o;
        gp[kx * 64] = re;
        gp[(16 + kx) * 64] = -im;
    }
}

// ---------------- k_final: planar MFMA GEMM + LDS-transpose epilogue ----------------
// R19: R5's scalar u16 epilogue caused 2x write amplification (WRITE 135 MB vs
// 67 ideal: 32B spans per store < 64B sectors) + 64 store insts/thread. Now:
// split into a [64][128] u16 LDS buffer per plane, then uint4 coalesced stores
// (256B-contiguous spans, 8 stores/thread).
__global__ __launch_bounds__(256, 4)
void k_final(ushort* __restrict__ hs_h, ushort* __restrict__ hs_l,
             const float* __restrict__ Gq,
             const uint4* __restrict__ wws_h, const uint4* __restrict__ wws_l,
             const float* __restrict__ wb,
             const uint4* __restrict__ trigs_h, const uint4* __restrict__ trigs_l) {
    __shared__ uint4 smem[2560];       // 40 KB unified
    uint4* sH0h = smem;
    uint4* sH0l = smem + 512;
    uint4* sH1h = smem + 1024;
    uint4* sH1l = smem + 1536;
    uint4* sGh  = smem + 2048;
    uint4* sGl  = smem + 2304;
    int blk = blockIdx.x;              // b(8) * y(256) * xq(2), xq fastest
    int xq = blk & 1, y = (blk >> 1) & 255, b = blk >> 9;
    int x0 = xq * 128;
    int t = threadIdx.x;
    int os = t & 63, q = t >> 6;       // Gq staging
    int w = t >> 6, l = t & 63;        // wave w owns o-rows [w*16, w*16+16)
    int lr = l & 15, lq = l >> 4;
    int xs = t & 127, half = t >> 7;   // H staging: x=xs, channels half*16..+15
    f32x4 acc[8];
    {
        int ob = w * 16 + lq * 4;
        f32x4 ini;
        ini[0] = wb[ob]; ini[1] = wb[ob + 1]; ini[2] = wb[ob + 2]; ini[3] = wb[ob + 3];
#pragma unroll
        for (int xt = 0; xt < 8; ++xt) acc[xt] = ini;
    }
    // ---- upfront loads: Gq, A-frags, H phase-0 channel rows
    float gv[8];
    {
        const float* gsrc = Gq + ((size_t)(b * 256 + y) * 32 + q * 8) * 64 + os;
#pragma unroll
        for (int kk = 0; kk < 8; ++kk) gv[kk] = gsrc[kk * 64];
    }
    uint4 A0h = wws_h[lq * 64 + w * 16 + lr];
    uint4 A0l = wws_l[lq * 64 + w * 16 + lr];
    uint4 A1h = wws_h[(4 + lq) * 64 + w * 16 + lr];
    uint4 A1l = wws_l[(4 + lq) * 64 + w * 16 + lr];
    size_t hb0 = (size_t)(b * 64 + half * 16) * HW + y * 256 + x0 + xs;
    unsigned hv[16], lv[16];
#pragma unroll
    for (int j = 0; j < 16; ++j) {
        hv[j] = hs_h[hb0 + (size_t)j * HW];
        lv[j] = hs_l[hb0 + (size_t)j * HW];
    }
    // ---- stage Gq (split) + H ph0 cells
    {
        uint4 ghq, glq; split_pack8(gv, ghq, glq);
        sGh[q * 64 + os] = ghq; sGl[q * 64 + os] = glq;
    }
#pragma unroll
    for (int c2 = 0; c2 < 2; ++c2) {
        int cell = (half * 2 + c2) * 128 + xs;
        sH0h[cell] = pack8(hv + c2 * 8);
        sH0l[cell] = pack8(lv + c2 * 8);
    }
    // ---- issue H phase-1 loads (channels 32 + half*16 + j)
    unsigned hv1[16], lv1[16];
    size_t hb1 = hb0 + (size_t)32 * HW;
#pragma unroll
    for (int j = 0; j < 16; ++j) {
        hv1[j] = hs_h[hb1 + (size_t)j * HW];
        lv1[j] = hs_l[hb1 + (size_t)j * HW];
    }
    bar_lgkm();
    // ---- phase 0 MFMA
#pragma unroll
    for (int xt = 0; xt < 8; ++xt) {
        bf16x8 Bh = __builtin_bit_cast(bf16x8, sH0h[lq * 128 + xt * 16 + lr]);
        bf16x8 Bl = __builtin_bit_cast(bf16x8, sH0l[lq * 128 + xt * 16 + lr]);
        bf16x8 Ah = __builtin_bit_cast(bf16x8, A0h);
        bf16x8 Al = __builtin_bit_cast(bf16x8, A0l);
        acc[xt] = __builtin_amdgcn_mfma_f32_16x16x32_bf16(Ah, Bh, acc[xt], 0, 0, 0);
        acc[xt] = __builtin_amdgcn_mfma_f32_16x16x32_bf16(Ah, Bl, acc[xt], 0, 0, 0);
        acc[xt] = __builtin_amdgcn_mfma_f32_16x16x32_bf16(Al, Bh, acc[xt], 0, 0, 0);
    }
    // ---- stage H ph1 into second buffer
#pragma unroll
    for (int c2 = 0; c2 < 2; ++c2) {
        int cell = (half * 2 + c2) * 128 + xs;
        sH1h[cell] = pack8(hv1 + c2 * 8);
        sH1l[cell] = pack8(lv1 + c2 * 8);
    }
    bar_lgkm();
    // ---- phase 1 MFMA
#pragma unroll
    for (int xt = 0; xt < 8; ++xt) {
        bf16x8 Bh = __builtin_bit_cast(bf16x8, sH1h[lq * 128 + xt * 16 + lr]);
        bf16x8 Bl = __builtin_bit_cast(bf16x8, sH1l[lq * 128 + xt * 16 + lr]);
        bf16x8 Ah = __builtin_bit_cast(bf16x8, A1h);
        bf16x8 Al = __builtin_bit_cast(bf16x8, A1l);
        acc[xt] = __builtin_amdgcn_mfma_f32_16x16x32_bf16(Ah, Bh, acc[xt], 0, 0, 0);
        acc[xt] = __builtin_amdgcn_mfma_f32_16x16x32_bf16(Ah, Bl, acc[xt], 0, 0, 0);
        acc[xt] = __builtin_amdgcn_mfma_f32_16x16x32_bf16(Al, Bh, acc[xt], 0, 0, 0);
    }
    // ---- phase 2 MFMA: A = Gq cells from LDS, B = trigs cells direct
    {
        bf16x8 Ah = __builtin_bit_cast(bf16x8, sGh[lq * 64 + w * 16 + lr]);
        bf16x8 Al = __builtin_bit_cast(bf16x8, sGl[lq * 64 + w * 16 + lr]);
#pragma unroll
        for (int xt = 0; xt < 8; ++xt) {
            bf16x8 Bh = __builtin_bit_cast(bf16x8, trigs_h[lq * 256 + x0 + xt * 16 + lr]);
            bf16x8 Bl = __builtin_bit_cast(bf16x8, trigs_l[lq * 256 + x0 + xt * 16 + lr]);
            acc[xt] = __builtin_amdgcn_mfma_f32_16x16x32_bf16(Ah, Bh, acc[xt], 0, 0, 0);
            acc[xt] = __builtin_amdgcn_mfma_f32_16x16x32_bf16(Ah, Bl, acc[xt], 0, 0, 0);
            acc[xt] = __builtin_amdgcn_mfma_f32_16x16x32_bf16(Al, Bh, acc[xt], 0, 0, 0);
        }
    }
    // ---- epilogue: relu + split into LDS transpose buffer, then coalesced stores
    __syncthreads();                       // all sH/sG reads done; reuse smem[0..2048)
    ushort* eh = (ushort*)smem;            // [64 o][128 x] hi plane (16 KB)
    ushort* el = (ushort*)(smem + 1024);   // [64 o][128 x] lo plane (16 KB)
#pragma unroll
    for (int xt = 0; xt < 8; ++xt)
#pragma unroll
        for (int g = 0; g < 4; ++g) {
            int o = w * 16 + lq * 4 + g;
            float r = fmaxf(acc[xt][g], 0.f);
            ushort hh, ll; split1(r, hh, ll);
            eh[o * 128 + xt * 16 + lr] = hh;
            el[o * 128 + xt * 16 + lr] = ll;
        }
    __syncthreads();
#pragma unroll
    for (int p = 0; p < 4; ++p) {
        int f = t + p * 256;               // f in [0,1024): o = f>>4, seg = f&15
        int o = f >> 4, seg = f & 15;
        size_t base = (size_t)(b * 64 + o) * HW + y * 256 + x0;
        *(uint4*)(hs_h + base + seg * 8) = smem[f];
        *(uint4*)(hs_l + base + seg * 8) = smem[1024 + f];
    }
}

// ---------------- fc1+fc2: planar-in MFMA GEMM + in-reg fc2 reduce ----------------
__global__ __launch_bounds__(256, 3)
void k_fc12(const ushort* __restrict__ hs_h, const ushort* __restrict__ hs_l,
            const uint4* __restrict__ w1s_h, const uint4* __restrict__ w1s_l,
            const float* __restrict__ b1, const float* __restrict__ w2,
            const float* __restrict__ b2, float* __restrict__ out) {
    __shared__ uint4 sH0h[512], sH0l[512], sH1h[512], sH1l[512];  // 32 KB
    int blk = blockIdx.x;                  // b(8) * y(256) * xq(2), xq fastest
    int xq = blk & 1, y = (blk >> 1) & 255, b = blk >> 9;
    int x0 = xq * 128;
    int t = threadIdx.x;
    int w = t >> 6, l = t & 63;
    int lr = l & 15, lq = l >> 4;
    int mb = w * 32;
    int xs = t & 127, half = t >> 7;
    f32x4 acc[2][8];
#pragma unroll
    for (int u = 0; u < 2; ++u) {
        int m0 = mb + u * 16 + lq * 4;
        f32x4 ini;
        ini[0] = b1[m0]; ini[1] = b1[m0 + 1]; ini[2] = b1[m0 + 2]; ini[3] = b1[m0 + 3];
#pragma unroll
        for (int xt = 0; xt < 8; ++xt) acc[u][xt] = ini;
    }
    // ---- upfront: A-frags + H phase-0 rows
    uint4 a0h[2], a0l[2], a1h[2], a1l[2];
#pragma unroll
    for (int u = 0; u < 2; ++u) {
        a0h[u] = w1s_h[lq * 128 + mb + u * 16 + lr];
        a0l[u] = w1s_l[lq * 128 + mb + u * 16 + lr];
        a1h[u] = w1s_h[(4 + lq) * 128 + mb + u * 16 + lr];
        a1l[u] = w1s_l[(4 + lq) * 128 + mb + u * 16 + lr];
    }
    size_t hb0 = (size_t)(b * 64 + half * 16) * HW + y * 256 + x0 + xs;
    unsigned hv[16], lv[16];
#pragma unroll
    for (int j = 0; j < 16; ++j) {
        hv[j] = hs_h[hb0 + (size_t)j * HW];
        lv[j] = hs_l[hb0 + (size_t)j * HW];
    }
#pragma unroll
    for (int c2 = 0; c2 < 2; ++c2) {
        int cell = (half * 2 + c2) * 128 + xs;
        sH0h[cell] = pack8(hv + c2 * 8);
        sH0l[cell] = pack8(lv + c2 * 8);
    }
    unsigned hv1[16], lv1[16];
    size_t hb1 = hb0 + (size_t)32 * HW;
#pragma unroll
    for (int j = 0; j < 16; ++j) {
        hv1[j] = hs_h[hb1 + (size_t)j * HW];
        lv1[j] = hs_l[hb1 + (size_t)j * HW];
    }
    bar_lgkm();
#pragma unroll
    for (int xt = 0; xt < 8; ++xt) {
        bf16x8 Bh = __builtin_bit_cast(bf16x8, sH0h[lq * 128 + xt * 16 + lr]);
        bf16x8 Bl = __builtin_bit_cast(bf16x8, sH0l[lq * 128 + xt * 16 + lr]);
#pragma unroll
        for (int u = 0; u < 2; ++u) {
            bf16x8 Ah = __builtin_bit_cast(bf16x8, a0h[u]);
            bf16x8 Al = __builtin_bit_cast(bf16x8, a0l[u]);
            acc[u][xt] = __builtin_amdgcn_mfma_f32_16x16x32_bf16(Ah, Bh, acc[u][xt], 0, 0, 0);
            acc[u][xt] = __builtin_amdgcn_mfma_f32_16x16x32_bf16(Ah, Bl, acc[u][xt], 0, 0, 0);
            acc[u][xt] = __builtin_amdgcn_mfma_f32_16x16x32_bf16(Al, Bh, acc[u][xt], 0, 0, 0);
        }
    }
#pragma unroll
    for (int c2 = 0; c2 < 2; ++c2) {
        int cell = (half * 2 + c2) * 128 + xs;
        sH1h[cell] = pack8(hv1 + c2 * 8);
        sH1l[cell] = pack8(lv1 + c2 * 8);
    }
    bar_lgkm();
#pragma unroll
    for (int xt = 0; xt < 8; ++xt) {
        bf16x8 Bh = __builtin_bit_cast(bf16x8, sH1h[lq * 128 + xt * 16 + lr]);
        bf16x8 Bl = __builtin_bit_cast(bf16x8, sH1l[lq * 128 + xt * 16 + lr]);
#pragma unroll
        for (int u = 0; u < 2; ++u) {
            bf16x8 Ah = __builtin_bit_cast(bf16x8, a1h[u]);
            bf16x8 Al = __builtin_bit_cast(bf16x8, a1l[u]);
            acc[u][xt] = __builtin_amdgcn_mfma_f32_16x16x32_bf16(Ah, Bh, acc[u][xt], 0, 0, 0);
            acc[u][xt] = __builtin_amdgcn_mfma_f32_16x16x32_bf16(Ah, Bl, acc[u][xt], 0, 0, 0);
            acc[u][xt] = __builtin_amdgcn_mfma_f32_16x16x32_bf16(Al, Bh, acc[u][xt], 0, 0, 0);
        }
    }
    // relu + fc2 partials
    float pj[3][8];
#pragma unroll
    for (int j = 0; j < 3; ++j)
#pragma unroll
        for (int xt = 0; xt < 8; ++xt) pj[j][xt] = 0.f;
#pragma unroll
    for (int u = 0; u < 2; ++u)
#pragma unroll
        for (int g = 0; g < 4; ++g) {
            int m = mb + u * 16 + lq * 4 + g;
            float w20 = w2[m], w21 = w2[NMLP + m], w22 = w2[2 * NMLP + m];
#pragma unroll
            for (int xt = 0; xt < 8; ++xt) {
                float r = fmaxf(acc[u][xt][g], 0.f);
                pj[0][xt] = fmaf(w20, r, pj[0][xt]);
                pj[1][xt] = fmaf(w21, r, pj[1][xt]);
                pj[2][xt] = fmaf(w22, r, pj[2][xt]);
            }
        }
#pragma unroll
    for (int j = 0; j < 3; ++j)
#pragma unroll
        for (int xt = 0; xt < 8; ++xt) {
            float v = pj[j][xt];
            v += __shfl_xor(v, 16);
            v += __shfl_xor(v, 32);
            pj[j][xt] = v;
        }
    float* part = (float*)sH0h;   // reuses sH0 (all reads done past barrier 2)
    if (lq == 0) {
#pragma unroll
        for (int j = 0; j < 3; ++j)
#pragma unroll
            for (int xt = 0; xt < 8; ++xt)
                part[(w * 3 + j) * 128 + xt * 16 + lr] = pj[j][xt];
    }
    __syncthreads();
#pragma unroll
    for (int r = 0; r < 2; ++r) {
        int idx = t + r * 256;
        if (idx < 384) {
            int j = idx >> 7, xx = idx & 127;
            float s = b2[j];
#pragma unroll
            for (int ww2 = 0; ww2 < 4; ++ww2) s += part[(ww2 * 3 + j) * 128 + xx];
            out[(size_t)(b * 3 + j) * HW + y * 256 + x0 + xx] = s;
        }
    }
}

extern "C" void kernel_launch(void* const* d_in, const int* in_sizes, int n_in,
                              void* d_out, int out_size, void* d_ws, size_t ws_size,
                              hipStream_t stream) {
    const float* x     = (const float*)d_in[0];
    const float* fc0_w = (const float*)d_in[1];
    const float* fc0_b = (const float*)d_in[2];
    const float* swre  = (const float*)d_in[3];
    const float* swim  = (const float*)d_in[4];
    const float* ww    = (const float*)d_in[5];
    const float* wb    = (const float*)d_in[6];
    const float* fc1w  = (const float*)d_in[7];
    const float* fc1b  = (const float*)d_in[8];
    const float* fc2w  = (const float*)d_in[9];
    const float* fc2b  = (const float*)d_in[10];

    float* ws = (float*)d_ws;
    float2* tab     = (float2*)ws;                    // 512 floats
    ushort* hs_h    = (ushort*)(ws + 512);            // 33.5M u16 (67 MB)
    ushort* hs_l    = (ushort*)(ws + 512 + 16777216); // 33.5M u16 (67 MB)
    float*  T1F     = ws + 33554944;                  // 4,194,304
    float2* X       = (float2*)(ws + 37749248);       // 262,144 floats
    float2* Y       = (float2*)(ws + 38011392);       // 262,144 floats
    float*  Gq      = ws + 38273536;                  // 4,194,304
    float*  trig    = ws + 42467840;                  // 8,192
    uint4*  trigs_h = (uint4*)(ws + 42476032);        // 1024 cells
    uint4*  trigs_l = (uint4*)(ws + 42480128);        // 1024 cells
    uint4*  wws_h   = (uint4*)(ws + 42484224);        // 2048 cells
    uint4*  wws_l   = (uint4*)(ws + 42492416);        // 2048 cells
    uint4*  w1s_h   = (uint4*)(ws + 42500608);        // 1024 cells
    uint4*  w1s_l   = (uint4*)(ws + 42504704);        // 1024 cells
    uint4*  ETh     = (uint4*)(ws + 42508800);        // 1024 cells
    uint4*  ETl     = (uint4*)(ws + 42512896);        // 1024 cells

    k_table<<<dim3(1), dim3(256), 0, stream>>>(tab);
    k_prep0<<<dim3(48), dim3(256), 0, stream>>>(tab, fc1w, ww, trig,
                                                trigs_h, trigs_l, wws_h, wws_l,
                                                w1s_h, w1s_l);
    k_prep_et<<<dim3(4), dim3(256), 0, stream>>>(tab, ETh, ETl);
    k_fc0<<<dim3(256), dim3(256), 0, stream>>>(x, fc0_w, fc0_b, hs_h, hs_l);

    for (int d = 0; d < NDEPTH; ++d) {
        k_fwd_y<<<dim3(1024), dim3(256), 0, stream>>>(hs_h, hs_l, ETh, ETl, T1F);
        k_fwd_x<<<dim3(512), dim3(256), 0, stream>>>(T1F, trig, X);
        k_mix<<<dim3(256), dim3(256), 0, stream>>>(X, swre + (size_t)d * C * C * 256,
                                                   swim + (size_t)d * C * C * 256, Y);
        k_invy<<<dim3(512), dim3(256), 0, stream>>>(Y, tab, Gq);
        k_final<<<dim3(4096), dim3(256), 0, stream>>>(hs_h, hs_l, Gq,
                                                      wws_h + (size_t)d * 512,
                                                      wws_l + (size_t)d * 512,
                                                      wb + d * C, trigs_h, trigs_l);
    }
    k_fc12<<<dim3(4096), dim3(256), 0, stream>>>(hs_h, hs_l, w1s_h, w1s_l,
                                                 fc1b, fc2w, fc2b, (float*)d_out);
}

// Round 7
// 666.225 us; speedup vs baseline: 1.0413x; 1.0413x over previous
//
#include <hip/hip_runtime.h>

#define Hd 256
#define Wd 256
#define HW 65536
#define C 64
#define B 8
#define M 16
#define NDEPTH 4
#define NMLP 128

typedef __attribute__((ext_vector_type(8))) __bf16 bf16x8;
typedef __attribute__((ext_vector_type(4))) float f32x4;

// lgkm-only barrier: ds visibility without draining vmcnt (in-flight prefetch).
__device__ inline void bar_lgkm() {
    asm volatile("s_waitcnt lgkmcnt(0)" ::: "memory");
    __builtin_amdgcn_s_barrier();
}

// split fp32 -> bf16 hi (RNE) + bf16 lo (RNE of residual); pack 8 -> uint4/plane.
__device__ inline void split_pack8(const float* v, uint4& hq, uint4& lq) {
    unsigned hw[4], lw[4];
#pragma unroll
    for (int i = 0; i < 4; ++i) {
        float a = v[2 * i], bb = v[2 * i + 1];
        unsigned ua = __float_as_uint(a);
        unsigned ha = (ua + 0x7fffu + ((ua >> 16) & 1u)) & 0xffff0000u;
        float ra = a - __uint_as_float(ha);
        unsigned ural = __float_as_uint(ra);
        unsigned la = (ural + 0x7fffu + ((ural >> 16) & 1u)) >> 16;
        unsigned ub = __float_as_uint(bb);
        unsigned hb = (ub + 0x7fffu + ((ub >> 16) & 1u)) & 0xffff0000u;
        float rb = bb - __uint_as_float(hb);
        unsigned urbl = __float_as_uint(rb);
        unsigned lb = (urbl + 0x7fffu + ((urbl >> 16) & 1u)) >> 16;
        hw[i] = (ha >> 16) | (hb & 0xffff0000u);
        lw[i] = la | (lb << 16);
    }
    hq = make_uint4(hw[0], hw[1], hw[2], hw[3]);
    lq = make_uint4(lw[0], lw[1], lw[2], lw[3]);
}

// scalar split
__device__ inline void split1(float s, ushort& h, ushort& l) {
    unsigned ua = __float_as_uint(s);
    unsigned ha = (ua + 0x7fffu + ((ua >> 16) & 1u)) & 0xffff0000u;
    float r = s - __uint_as_float(ha);
    unsigned ur = __float_as_uint(r);
    h = (ushort)(ha >> 16);
    l = (ushort)((ur + 0x7fffu + ((ur >> 16) & 1u)) >> 16);
}

// pack 8 zero-extended u16 -> uint4
__device__ inline uint4 pack8(const unsigned* v) {
    uint4 r;
    r.x = v[0] | (v[1] << 16);
    r.y = v[2] | (v[3] << 16);
    r.z = v[4] | (v[5] << 16);
    r.w = v[6] | (v[7] << 16);
    return r;
}

// h storage: planar split-bf16 ushort planes [b][c][y][x] (x contiguous).

// ---------------- twiddle table ----------------
__global__ void k_table(float2* __restrict__ tab) {
    int t = threadIdx.x;
    double a = (6.283185307179586476925286766559 / 256.0) * (double)t;
    tab[t] = make_float2((float)cos(a), (float)sin(a));
}

// ---------------- once: trig + pre-split cells for W-sides ----------------
__global__ void k_prep0(const float2* __restrict__ tab, const float* __restrict__ fc1w,
                        const float* __restrict__ ww, float* __restrict__ trig,
                        uint4* __restrict__ trigs_h, uint4* __restrict__ trigs_l,
                        uint4* __restrict__ wws_h, uint4* __restrict__ wws_l,
                        uint4* __restrict__ w1s_h, uint4* __restrict__ w1s_l) {
    int blk = blockIdx.x, t = threadIdx.x;
    if (blk < 32) {                    // trig[kk][x]: cos kk<16, +sin kk>=16 (fp32, fwd_x)
        int k = blk & 15;
        float2 e = tab[(k * t) & 255];
        trig[blk * 256 + t] = (blk < 16) ? e.x : e.y;
    } else if (blk < 36) {             // trigs cells [kc 4][x 256], k = trig row
        int idx = (blk - 32) * 256 + t;
        int kc = idx >> 8, x = idx & 255;
        float v[8];
#pragma unroll
        for (int j = 0; j < 8; ++j) {
            int row = kc * 8 + j;
            float2 e = tab[((row & 15) * x) & 255];
            v[j] = (row < 16) ? e.x : e.y;
        }
        uint4 hq, lq; split_pack8(v, hq, lq);
        trigs_h[idx] = hq; trigs_l[idx] = lq;
    } else if (blk < 44) {             // wws cells [(d*2+ph)*4+kc][o 64], k = i
        int idx = (blk - 36) * 256 + t;
        int o = idx & 63, kc = (idx >> 6) & 3, ph = (idx >> 8) & 1, d = idx >> 9;
        float v[8];
#pragma unroll
        for (int j = 0; j < 8; ++j)
            v[j] = ww[d * 4096 + o * 64 + ph * 32 + kc * 8 + j];
        uint4 hq, lq; split_pack8(v, hq, lq);
        wws_h[idx] = hq; wws_l[idx] = lq;
    } else {                           // w1s cells [(ph*4+kc)][m 128], k = i
        int idx = (blk - 44) * 256 + t;
        int m = idx & 127, kc = (idx >> 7) & 3, ph = idx >> 9;
        float v[8];
#pragma unroll
        for (int j = 0; j < 8; ++j)
            v[j] = fc1w[m * 64 + ph * 32 + kc * 8 + j];
        uint4 hq, lq; split_pack8(v, hq, lq);
        w1s_h[idx] = hq; w1s_l[idx] = lq;
    }
}

// ---------------- once: split-bf16 A-fragments of the y-DFT matrix ----------------
__global__ void k_prep_et(const float2* __restrict__ tab,
                          uint4* __restrict__ ETh, uint4* __restrict__ ETl) {
    int c = blockIdx.x * 256 + threadIdx.x;
    if (c >= 1024) return;
    int ph = c >> 7, kc = (c >> 5) & 3, m = c & 31;
    float v[8];
#pragma unroll
    for (int j = 0; j < 8; ++j) {
        int y = ph * 32 + kc * 8 + j;
        float2 e = tab[((m & 15) * y) & 255];
        v[j] = (m < 16) ? e.x : -e.y;
    }
    uint4 hq, lq;
    split_pack8(v, hq, lq);
    ETh[c] = hq; ETl[c] = lq;
}

// ---------------- fc0: planar split output, 8 pixels/thread ----------------
__global__ void k_fc0(const float* __restrict__ x, const float* __restrict__ w,
                      const float* __restrict__ bias,
                      ushort* __restrict__ hs_h, ushort* __restrict__ hs_l) {
    int gp = blockIdx.x * 256 + threadIdx.x;   // 65536 groups of 8 pixels
    int b = gp >> 13, pg = gp & 8191;
    int pix0 = pg * 8;
    float xv[3][8];
#pragma unroll
    for (int ch = 0; ch < 3; ++ch) {
        float4 a = *(const float4*)(x + (size_t)(b * 3 + ch) * HW + pix0);
        float4 c4 = *(const float4*)(x + (size_t)(b * 3 + ch) * HW + pix0 + 4);
        xv[ch][0] = a.x; xv[ch][1] = a.y; xv[ch][2] = a.z; xv[ch][3] = a.w;
        xv[ch][4] = c4.x; xv[ch][5] = c4.y; xv[ch][6] = c4.z; xv[ch][7] = c4.w;
    }
    for (int o = 0; o < C; ++o) {
        float w0 = w[o * 3 + 0], w1 = w[o * 3 + 1], w2 = w[o * 3 + 2], bv = bias[o];
        float v[8];
#pragma unroll
        for (int j = 0; j < 8; ++j)
            v[j] = fmaf(w0, xv[0][j], fmaf(w1, xv[1][j], fmaf(w2, xv[2][j], bv)));
        uint4 hq, lq; split_pack8(v, hq, lq);
        *(uint4*)(hs_h + (size_t)(b * 64 + o) * HW + pix0) = hq;
        *(uint4*)(hs_l + (size_t)(b * 64 + o) * HW + pix0) = lq;
    }
}

// ---------------- forward y-DFT: LDS-free split-bf16 MFMA GEMM ----------------
__global__ __launch_bounds__(256, 4)
void k_fwd_y(const ushort* __restrict__ hs_h, const ushort* __restrict__ hs_l,
             const uint4* __restrict__ ETh, const uint4* __restrict__ ETl,
             float* __restrict__ T1F) {
    int blk = blockIdx.x;                  // bc(512) * xh(2), xh fastest
    int xh = blk & 1, bc = blk >> 1;
    int x0 = xh * 128;
    int t = threadIdx.x;
    int w = t >> 6, l = t & 63;            // wave w owns x in [w*32, w*32+32)
    int lr = l & 15, lq = l >> 4;
    const ushort* pH = hs_h + (size_t)bc * HW + x0 + w * 32 + lr;
    const ushort* pL = hs_l + (size_t)bc * HW + x0 + w * 32 + lr;
    f32x4 acc[2][2];
#pragma unroll
    for (int u = 0; u < 2; ++u)
#pragma unroll
        for (int xt = 0; xt < 2; ++xt) {
            acc[u][xt][0] = 0.f; acc[u][xt][1] = 0.f;
            acc[u][xt][2] = 0.f; acc[u][xt][3] = 0.f;
        }
    unsigned h0[2][8], l0[2][8], h1[2][8], l1[2][8];
    auto loadp = [&](unsigned hv[2][8], unsigned lv[2][8], int ph) {
#pragma unroll
        for (int xt = 0; xt < 2; ++xt)
#pragma unroll
            for (int j = 0; j < 8; ++j) {
                int off = (ph * 32 + lq * 8 + j) * 256 + xt * 16;
                hv[xt][j] = pH[off];
                lv[xt][j] = pL[off];
            }
    };
    loadp(h0, l0, 0);
#pragma unroll
    for (int ph = 0; ph < 8; ++ph) {
        unsigned (*ch)[8] = (ph & 1) ? h1 : h0;
        unsigned (*cl)[8] = (ph & 1) ? l1 : l0;
        unsigned (*nh)[8] = (ph & 1) ? h0 : h1;
        unsigned (*nl)[8] = (ph & 1) ? l0 : l1;
        if (ph < 7) loadp(nh, nl, ph + 1);
        bf16x8 Ah[2], Al[2];
#pragma unroll
        for (int u = 0; u < 2; ++u) {
            int ci = ph * 128 + lq * 32 + u * 16 + lr;
            Ah[u] = __builtin_bit_cast(bf16x8, ETh[ci]);
            Al[u] = __builtin_bit_cast(bf16x8, ETl[ci]);
        }
#pragma unroll
        for (int xt = 0; xt < 2; ++xt) {
            bf16x8 Bh = __builtin_bit_cast(bf16x8, pack8(ch[xt]));
            bf16x8 Bl = __builtin_bit_cast(bf16x8, pack8(cl[xt]));
#pragma unroll
            for (int u = 0; u < 2; ++u) {
                acc[u][xt] = __builtin_amdgcn_mfma_f32_16x16x32_bf16(Ah[u], Bh, acc[u][xt], 0, 0, 0);
                acc[u][xt] = __builtin_amdgcn_mfma_f32_16x16x32_bf16(Ah[u], Bl, acc[u][xt], 0, 0, 0);
                acc[u][xt] = __builtin_amdgcn_mfma_f32_16x16x32_bf16(Al[u], Bh, acc[u][xt], 0, 0, 0);
            }
        }
    }
#pragma unroll
    for (int u = 0; u < 2; ++u)
#pragma unroll
        for (int xt = 0; xt < 2; ++xt)
#pragma unroll
            for (int g = 0; g < 4; ++g)
                T1F[(size_t)bc * 8192 + (u * 16 + lq * 4 + g) * 256 + x0 + w * 32 + xt * 16 + lr] =
                    acc[u][xt][g];
}

// ---------------- forward x-DFT (unchanged) ----------------
__global__ __launch_bounds__(256, 2)
void k_fwd_x(const float* __restrict__ T1F, const float* __restrict__ trig,
             float2* __restrict__ X) {
    __shared__ float sT[32 * 260];
    __shared__ float sG[32 * 260];
    int bc = blockIdx.x, t = threadIdx.x;
#pragma unroll
    for (int p = 0; p < 8; ++p) {
        int f = t + p * 256;
        int row = f >> 6, seg = f & 63;
        ((float4*)(sT + row * 260))[seg] = *(const float4*)(T1F + (size_t)bc * 8192 + f * 4);
        ((float4*)(sG + row * 260))[seg] = *(const float4*)(trig + row * 256 + seg * 4);
    }
    __syncthreads();
    int ky = t >> 4, kx = t & 15;
    const float* Tr = sT + ky * 260;
    const float* Ti = sT + (16 + ky) * 260;
    const float* Cs = sG + kx * 260;
    const float* Sn = sG + (16 + kx) * 260;
    float xr0 = 0.f, xi0 = 0.f, xr1 = 0.f, xi1 = 0.f;
    for (int q = 0; q < 64; q += 2) {
        float4 tr = *(const float4*)(Tr + q * 4);
        float4 ti = *(const float4*)(Ti + q * 4);
        float4 cs = *(const float4*)(Cs + q * 4);
        float4 sn = *(const float4*)(Sn + q * 4);
        xr0 = fmaf(tr.x, cs.x, xr0); xr0 = fmaf(ti.x, sn.x, xr0);
        xi0 = fmaf(ti.x, cs.x, xi0); xi0 = fmaf(-tr.x, sn.x, xi0);
        xr0 = fmaf(tr.y, cs.y, xr0); xr0 = fmaf(ti.y, sn.y, xr0);
        xi0 = fmaf(ti.y, cs.y, xi0); xi0 = fmaf(-tr.y, sn.y, xi0);
        xr0 = fmaf(tr.z, cs.z, xr0); xr0 = fmaf(ti.z, sn.z, xr0);
        xi0 = fmaf(ti.z, cs.z, xi0); xi0 = fmaf(-tr.z, sn.z, xi0);
        xr0 = fmaf(tr.w, cs.w, xr0); xr0 = fmaf(ti.w, sn.w, xr0);
        xi0 = fmaf(ti.w, cs.w, xi0); xi0 = fmaf(-tr.w, sn.w, xi0);
        float4 tr1 = *(const float4*)(Tr + q * 4 + 4);
        float4 ti1 = *(const float4*)(Ti + q * 4 + 4);
        float4 cs1 = *(const float4*)(Cs + q * 4 + 4);
        float4 sn1 = *(const float4*)(Sn + q * 4 + 4);
        xr1 = fmaf(tr1.x, cs1.x, xr1); xr1 = fmaf(ti1.x, sn1.x, xr1);
        xi1 = fmaf(ti1.x, cs1.x, xi1); xi1 = fmaf(-tr1.x, sn1.x, xi1);
        xr1 = fmaf(tr1.y, cs1.y, xr1); xr1 = fmaf(ti1.y, sn1.y, xr1);
        xi1 = fmaf(ti1.y, cs1.y, xi1); xi1 = fmaf(-tr1.y, sn1.y, xi1);
        xr1 = fmaf(tr1.z, cs1.z, xr1); xr1 = fmaf(ti1.z, sn1.z, xr1);
        xi1 = fmaf(ti1.z, cs1.z, xi1); xi1 = fmaf(-tr1.z, sn1.z, xi1);
        xr1 = fmaf(tr1.w, cs1.w, xr1); xr1 = fmaf(ti1.w, sn1.w, xr1);
        xi1 = fmaf(ti1.w, cs1.w, xi1); xi1 = fmaf(-tr1.w, sn1.w, xi1);
    }
    X[bc * 256 + t] = make_float2(xr0 + xr1, xi0 + xi1);
}

// ---------------- mode mixing (unchanged) ----------------
__global__ __launch_bounds__(256, 2)
void k_mix(const float2* __restrict__ X, const float* __restrict__ wre,
           const float* __restrict__ wim, float2* __restrict__ Y) {
    int o = blockIdx.x >> 2;
    int bq = blockIdx.x & 3;
    int m = threadIdx.x;
    int b0 = bq * 2, b1 = bq * 2 + 1;
    float yr0 = 0.f, yi0 = 0.f, yr1 = 0.f, yi1 = 0.f;
    for (int i = 0; i < C; ++i) {
        float wr = wre[(i * C + o) * 256 + m];
        float wi = wim[(i * C + o) * 256 + m];
        float2 x0 = X[(b0 * C + i) * 256 + m];
        float2 x1 = X[(b1 * C + i) * 256 + m];
        yr0 = fmaf(x0.x, wr, fmaf(-x0.y, wi, yr0));
        yi0 = fmaf(x0.x, wi, fmaf(x0.y, wr, yi0));
        yr1 = fmaf(x1.x, wr, fmaf(-x1.y, wi, yr1));
        yi1 = fmaf(x1.x, wi, fmaf(x1.y, wr, yi1));
    }
    Y[(b0 * C + o) * 256 + m] = make_float2(yr0, yi0);
    Y[(b1 * C + o) * 256 + m] = make_float2(yr1, yi1);
}

// ---------------- fused inverse-y + Gq production (unchanged) ----------------
__global__ __launch_bounds__(256, 2)
void k_invy(const float2* __restrict__ Y, const float2* __restrict__ tab,
            float* __restrict__ Gq) {
    __shared__ float2 st[256];
    int blk = blockIdx.x;              // 8b x 4pg x 16yt
    int yt = blk & 15, pg = (blk >> 4) & 3, b = blk >> 6;
    int t = threadIdx.x;
    st[t] = tab[t];
    int o = t & 63, kx = pg * 4 + (t >> 6);
    __syncthreads();
    float sc = (kx == 0 ? 1.0f : 2.0f) * (1.0f / 65536.0f);
    float yr[16], yi[16];
    const float2* yp = Y + (size_t)(b * 64 + o) * 256 + kx;
#pragma unroll
    for (int ky = 0; ky < 16; ++ky) {
        float2 v = yp[ky * 16];
        yr[ky] = v.x * sc;
        yi[ky] = v.y * sc;
    }
    int y0 = yt * 16;
    for (int yy = 0; yy < 16; ++yy) {
        int y = y0 + yy;
        float re = 0.f, im = 0.f;
#pragma unroll
        for (int ky = 0; ky < 16; ++ky) {
            float2 e = st[(ky * y) & 255];
            re = fmaf(yr[ky], e.x, re);
            re = fmaf(-yi[ky], e.y, re);
            im = fmaf(yr[ky], e.y, im);
            im = fmaf(yi[ky], e.x, im);
        }
        float* gp = Gq + (size_t)(b * 256 + y) * 32 * 64 + o;
        gp[kx * 64] = re;
        gp[(16 + kx) * 64] = -im;
    }
}

// ---------------- k_final (d<3): 32 KB LDS, Gq-direct A-frags, swizzled epilogue ----------------
// R20: sG LDS dropped (per-lane Gq A-frag load, coalesced 64B sectors, in-reg split)
// -> 32 KB = 5 blocks/CU. Epilogue transpose XOR-swizzled (col ^= lq*40): the 4 lq
// quadrants hit 4 disjoint 8-bank sets, 2 lanes/bank = conflict-free.
__global__ __launch_bounds__(256, 5)
void k_final(ushort* __restrict__ hs_h, ushort* __restrict__ hs_l,
             const float* __restrict__ Gq,
             const uint4* __restrict__ wws_h, const uint4* __restrict__ wws_l,
             const float* __restrict__ wb,
             const uint4* __restrict__ trigs_h, const uint4* __restrict__ trigs_l) {
    __shared__ uint4 smem[2048];       // 32 KB unified
    uint4* sH0h = smem;
    uint4* sH0l = smem + 512;
    uint4* sH1h = smem + 1024;
    uint4* sH1l = smem + 1536;
    int blk = blockIdx.x;              // b(8) * y(256) * xq(2), xq fastest
    int xq = blk & 1, y = (blk >> 1) & 255, b = blk >> 9;
    int x0 = xq * 128;
    int t = threadIdx.x;
    int w = t >> 6, l = t & 63;        // wave w owns o-rows [w*16, w*16+16)
    int lr = l & 15, lq = l >> 4;
    int xs = t & 127, half = t >> 7;   // H staging: x=xs, channels half*16..+15
    f32x4 acc[8];
    {
        int ob = w * 16 + lq * 4;
        f32x4 ini;
        ini[0] = wb[ob]; ini[1] = wb[ob + 1]; ini[2] = wb[ob + 2]; ini[3] = wb[ob + 3];
#pragma unroll
        for (int xt = 0; xt < 8; ++xt) acc[xt] = ini;
    }
    // ---- upfront loads: Gq A-frag (per-lane), wws A-frags, H ph0 rows
    float gv[8];
    {
        const float* gsrc = Gq + ((size_t)(b * 256 + y) * 32 + lq * 8) * 64 + w * 16 + lr;
#pragma unroll
        for (int kk = 0; kk < 8; ++kk) gv[kk] = gsrc[kk * 64];
    }
    uint4 A0h = wws_h[lq * 64 + w * 16 + lr];
    uint4 A0l = wws_l[lq * 64 + w * 16 + lr];
    uint4 A1h = wws_h[(4 + lq) * 64 + w * 16 + lr];
    uint4 A1l = wws_l[(4 + lq) * 64 + w * 16 + lr];
    size_t hb0 = (size_t)(b * 64 + half * 16) * HW + y * 256 + x0 + xs;
    unsigned hv[16], lv[16];
#pragma unroll
    for (int j = 0; j < 16; ++j) {
        hv[j] = hs_h[hb0 + (size_t)j * HW];
        lv[j] = hs_l[hb0 + (size_t)j * HW];
    }
#pragma unroll
    for (int c2 = 0; c2 < 2; ++c2) {
        int cell = (half * 2 + c2) * 128 + xs;
        sH0h[cell] = pack8(hv + c2 * 8);
        sH0l[cell] = pack8(lv + c2 * 8);
    }
    // ---- issue H phase-1 loads (channels 32 + half*16 + j)
    unsigned hv1[16], lv1[16];
    size_t hb1 = hb0 + (size_t)32 * HW;
#pragma unroll
    for (int j = 0; j < 16; ++j) {
        hv1[j] = hs_h[hb1 + (size_t)j * HW];
        lv1[j] = hs_l[hb1 + (size_t)j * HW];
    }
    bar_lgkm();
    // ---- phase 0 MFMA
#pragma unroll
    for (int xt = 0; xt < 8; ++xt) {
        bf16x8 Bh = __builtin_bit_cast(bf16x8, sH0h[lq * 128 + xt * 16 + lr]);
        bf16x8 Bl = __builtin_bit_cast(bf16x8, sH0l[lq * 128 + xt * 16 + lr]);
        bf16x8 Ah = __builtin_bit_cast(bf16x8, A0h);
        bf16x8 Al = __builtin_bit_cast(bf16x8, A0l);
        acc[xt] = __builtin_amdgcn_mfma_f32_16x16x32_bf16(Ah, Bh, acc[xt], 0, 0, 0);
        acc[xt] = __builtin_amdgcn_mfma_f32_16x16x32_bf16(Ah, Bl, acc[xt], 0, 0, 0);
        acc[xt] = __builtin_amdgcn_mfma_f32_16x16x32_bf16(Al, Bh, acc[xt], 0, 0, 0);
    }
    // ---- stage H ph1 into second buffer
#pragma unroll
    for (int c2 = 0; c2 < 2; ++c2) {
        int cell = (half * 2 + c2) * 128 + xs;
        sH1h[cell] = pack8(hv1 + c2 * 8);
        sH1l[cell] = pack8(lv1 + c2 * 8);
    }
    bar_lgkm();
    // ---- phase 1 MFMA
#pragma unroll
    for (int xt = 0; xt < 8; ++xt) {
        bf16x8 Bh = __builtin_bit_cast(bf16x8, sH1h[lq * 128 + xt * 16 + lr]);
        bf16x8 Bl = __builtin_bit_cast(bf16x8, sH1l[lq * 128 + xt * 16 + lr]);
        bf16x8 Ah = __builtin_bit_cast(bf16x8, A1h);
        bf16x8 Al = __builtin_bit_cast(bf16x8, A1l);
        acc[xt] = __builtin_amdgcn_mfma_f32_16x16x32_bf16(Ah, Bh, acc[xt], 0, 0, 0);
        acc[xt] = __builtin_amdgcn_mfma_f32_16x16x32_bf16(Ah, Bl, acc[xt], 0, 0, 0);
        acc[xt] = __builtin_amdgcn_mfma_f32_16x16x32_bf16(Al, Bh, acc[xt], 0, 0, 0);
    }
    // ---- phase 2 MFMA: A = Gq (in-reg split), B = trigs cells direct
    {
        uint4 gh4, gl4; split_pack8(gv, gh4, gl4);
        bf16x8 Ah = __builtin_bit_cast(bf16x8, gh4);
        bf16x8 Al = __builtin_bit_cast(bf16x8, gl4);
#pragma unroll
        for (int xt = 0; xt < 8; ++xt) {
            bf16x8 Bh = __builtin_bit_cast(bf16x8, trigs_h[lq * 256 + x0 + xt * 16 + lr]);
            bf16x8 Bl = __builtin_bit_cast(bf16x8, trigs_l[lq * 256 + x0 + xt * 16 + lr]);
            acc[xt] = __builtin_amdgcn_mfma_f32_16x16x32_bf16(Ah, Bh, acc[xt], 0, 0, 0);
            acc[xt] = __builtin_amdgcn_mfma_f32_16x16x32_bf16(Ah, Bl, acc[xt], 0, 0, 0);
            acc[xt] = __builtin_amdgcn_mfma_f32_16x16x32_bf16(Al, Bh, acc[xt], 0, 0, 0);
        }
    }
    // ---- epilogue: relu + split into swizzled [64][128] LDS planes, coalesced stores
    __syncthreads();                       // all sH reads done; reuse smem
    ushort* eh = (ushort*)smem;            // [64 o][128 col^swz] hi plane (16 KB)
    ushort* el = (ushort*)(smem + 1024);   // lo plane (16 KB)
    int swz = lq * 40;                     // bank-spread XOR (bits 3..6, 8-aligned)
#pragma unroll
    for (int xt = 0; xt < 8; ++xt)
#pragma unroll
        for (int g = 0; g < 4; ++g) {
            int o = w * 16 + lq * 4 + g;
            float r = fmaxf(acc[xt][g], 0.f);
            ushort hh, ll; split1(r, hh, ll);
            int col = (xt * 16 + lr) ^ swz;
            eh[o * 128 + col] = hh;
            el[o * 128 + col] = ll;
        }
    __syncthreads();
#pragma unroll
    for (int p = 0; p < 4; ++p) {
        int f = t + p * 256;               // o = f>>4, seg = f&15
        int o = f >> 4, seg = f & 15;
        int ko = ((o >> 2) & 3) * 40;      // writer's lq = (o>>2)&3
        int cb = (seg * 8) ^ ko;           // swizzled LDS block holding true cols seg*8..+7
        size_t base = (size_t)(b * 64 + o) * HW + y * 256 + x0;
        *(uint4*)(hs_h + base + seg * 8) = *(uint4*)(eh + o * 128 + cb);
        *(uint4*)(hs_l + base + seg * 8) = *(uint4*)(el + o * 128 + cb);
    }
}

// ---------------- k_final_fc (d=3): k_final + fused fc1/fc2, no h round-trip ----------------
// R20: the block holds all 64 channels of its (y, x-half) tile; h_new goes to LDS
// cells (not HBM) and fc1/fc2 run straight from LDS. Saves 134 MB write + 134 MB read.
__global__ __launch_bounds__(256, 3)
void k_final_fc(const ushort* __restrict__ hs_h, const ushort* __restrict__ hs_l,
                const float* __restrict__ Gq,
                const uint4* __restrict__ wws_h, const uint4* __restrict__ wws_l,
                const float* __restrict__ wb,
                const uint4* __restrict__ trigs_h, const uint4* __restrict__ trigs_l,
                const uint4* __restrict__ w1s_h, const uint4* __restrict__ w1s_l,
                const float* __restrict__ b1, const float* __restrict__ w2,
                const float* __restrict__ b2, float* __restrict__ out) {
    __shared__ uint4 smem[2048];       // 32 KB unified
    uint4* sH0h = smem;
    uint4* sH0l = smem + 512;
    uint4* sH1h = smem + 1024;
    uint4* sH1l = smem + 1536;
    int blk = blockIdx.x;
    int xq = blk & 1, y = (blk >> 1) & 255, b = blk >> 9;
    int x0 = xq * 128;
    int t = threadIdx.x;
    int w = t >> 6, l = t & 63;
    int lr = l & 15, lq = l >> 4;
    int xs = t & 127, half = t >> 7;
    f32x4 acc[8];
    {
        int ob = w * 16 + lq * 4;
        f32x4 ini;
        ini[0] = wb[ob]; ini[1] = wb[ob + 1]; ini[2] = wb[ob + 2]; ini[3] = wb[ob + 3];
#pragma unroll
        for (int xt = 0; xt < 8; ++xt) acc[xt] = ini;
    }
    float gv[8];
    {
        const float* gsrc = Gq + ((size_t)(b * 256 + y) * 32 + lq * 8) * 64 + w * 16 + lr;
#pragma unroll
        for (int kk = 0; kk < 8; ++kk) gv[kk] = gsrc[kk * 64];
    }
    uint4 A0h = wws_h[lq * 64 + w * 16 + lr];
    uint4 A0l = wws_l[lq * 64 + w * 16 + lr];
    uint4 A1h = wws_h[(4 + lq) * 64 + w * 16 + lr];
    uint4 A1l = wws_l[(4 + lq) * 64 + w * 16 + lr];
    size_t hb0 = (size_t)(b * 64 + half * 16) * HW + y * 256 + x0 + xs;
    unsigned hv[16], lv[16];
#pragma unroll
    for (int j = 0; j < 16; ++j) {
        hv[j] = hs_h[hb0 + (size_t)j * HW];
        lv[j] = hs_l[hb0 + (size_t)j * HW];
    }
#pragma unroll
    for (int c2 = 0; c2 < 2; ++c2) {
        int cell = (half * 2 + c2) * 128 + xs;
        sH0h[cell] = pack8(hv + c2 * 8);
        sH0l[cell] = pack8(lv + c2 * 8);
    }
    unsigned hv1[16], lv1[16];
    size_t hb1 = hb0 + (size_t)32 * HW;
#pragma unroll
    for (int j = 0; j < 16; ++j) {
        hv1[j] = hs_h[hb1 + (size_t)j * HW];
        lv1[j] = hs_l[hb1 + (size_t)j * HW];
    }
    bar_lgkm();
#pragma unroll
    for (int xt = 0; xt < 8; ++xt) {
        bf16x8 Bh = __builtin_bit_cast(bf16x8, sH0h[lq * 128 + xt * 16 + lr]);
        bf16x8 Bl = __builtin_bit_cast(bf16x8, sH0l[lq * 128 + xt * 16 + lr]);
        bf16x8 Ah = __builtin_bit_cast(bf16x8, A0h);
        bf16x8 Al = __builtin_bit_cast(bf16x8, A0l);
        acc[xt] = __builtin_amdgcn_mfma_f32_16x16x32_bf16(Ah, Bh, acc[xt], 0, 0, 0);
        acc[xt] = __builtin_amdgcn_mfma_f32_16x16x32_bf16(Ah, Bl, acc[xt], 0, 0, 0);
        acc[xt] = __builtin_amdgcn_mfma_f32_16x16x32_bf16(Al, Bh, acc[xt], 0, 0, 0);
    }
#pragma unroll
    for (int c2 = 0; c2 < 2; ++c2) {
        int cell = (half * 2 + c2) * 128 + xs;
        sH1h[cell] = pack8(hv1 + c2 * 8);
        sH1l[cell] = pack8(lv1 + c2 * 8);
    }
    bar_lgkm();
#pragma unroll
    for (int xt = 0; xt < 8; ++xt) {
        bf16x8 Bh = __builtin_bit_cast(bf16x8, sH1h[lq * 128 + xt * 16 + lr]);
        bf16x8 Bl = __builtin_bit_cast(bf16x8, sH1l[lq * 128 + xt * 16 + lr]);
        bf16x8 Ah = __builtin_bit_cast(bf16x8, A1h);
        bf16x8 Al = __builtin_bit_cast(bf16x8, A1l);
        acc[xt] = __builtin_amdgcn_mfma_f32_16x16x32_bf16(Ah, Bh, acc[xt], 0, 0, 0);
        acc[xt] = __builtin_amdgcn_mfma_f32_16x16x32_bf16(Ah, Bl, acc[xt], 0, 0, 0);
        acc[xt] = __builtin_amdgcn_mfma_f32_16x16x32_bf16(Al, Bh, acc[xt], 0, 0, 0);
    }
    {
        uint4 gh4, gl4; split_pack8(gv, gh4, gl4);
        bf16x8 Ah = __builtin_bit_cast(bf16x8, gh4);
        bf16x8 Al = __builtin_bit_cast(bf16x8, gl4);
#pragma unroll
        for (int xt = 0; xt < 8; ++xt) {
            bf16x8 Bh = __builtin_bit_cast(bf16x8, trigs_h[lq * 256 + x0 + xt * 16 + lr]);
            bf16x8 Bl = __builtin_bit_cast(bf16x8, trigs_l[lq * 256 + x0 + xt * 16 + lr]);
            acc[xt] = __builtin_amdgcn_mfma_f32_16x16x32_bf16(Ah, Bh, acc[xt], 0, 0, 0);
            acc[xt] = __builtin_amdgcn_mfma_f32_16x16x32_bf16(Ah, Bl, acc[xt], 0, 0, 0);
            acc[xt] = __builtin_amdgcn_mfma_f32_16x16x32_bf16(Al, Bh, acc[xt], 0, 0, 0);
        }
    }
    // ---- h_new (relu, split) into LDS cells [kc 8][x 128][8k] per plane
    __syncthreads();
    ushort* ch16 = (ushort*)smem;              // hi cells (16 KB)
    ushort* cl16 = (ushort*)(smem + 1024);     // lo cells (16 KB)
#pragma unroll
    for (int xt = 0; xt < 8; ++xt)
#pragma unroll
        for (int g = 0; g < 4; ++g) {
            int o = w * 16 + lq * 4 + g;
            float r = fmaxf(acc[xt][g], 0.f);
            ushort hh, ll; split1(r, hh, ll);
            int ci = ((o >> 3) * 128 + xt * 16 + lr) * 8 + (o & 7);
            ch16[ci] = hh;
            cl16[ci] = ll;
        }
    __syncthreads();
    // ---- fc1 GEMM from LDS cells (K=64, 2 phases), A = w1s
    uint4* cells_h = smem;
    uint4* cells_l = smem + 1024;
    int mb = w * 32;
    f32x4 acc2[2][8];
#pragma unroll
    for (int u = 0; u < 2; ++u) {
        int m0 = mb + u * 16 + lq * 4;
        f32x4 ini;
        ini[0] = b1[m0]; ini[1] = b1[m0 + 1]; ini[2] = b1[m0 + 2]; ini[3] = b1[m0 + 3];
#pragma unroll
        for (int xt = 0; xt < 8; ++xt) acc2[u][xt] = ini;
    }
#pragma unroll
    for (int ph = 0; ph < 2; ++ph) {
        bf16x8 Ah[2], Al[2];
#pragma unroll
        for (int u = 0; u < 2; ++u) {
            Ah[u] = __builtin_bit_cast(bf16x8, w1s_h[(ph * 4 + lq) * 128 + mb + u * 16 + lr]);
            Al[u] = __builtin_bit_cast(bf16x8, w1s_l[(ph * 4 + lq) * 128 + mb + u * 16 + lr]);
        }
#pragma unroll
        for (int xt = 0; xt < 8; ++xt) {
            bf16x8 Bh = __builtin_bit_cast(bf16x8, cells_h[(ph * 4 + lq) * 128 + xt * 16 + lr]);
            bf16x8 Bl = __builtin_bit_cast(bf16x8, cells_l[(ph * 4 + lq) * 128 + xt * 16 + lr]);
#pragma unroll
            for (int u = 0; u < 2; ++u) {
                acc2[u][xt] = __builtin_amdgcn_mfma_f32_16x16x32_bf16(Ah[u], Bh, acc2[u][xt], 0, 0, 0);
                acc2[u][xt] = __builtin_amdgcn_mfma_f32_16x16x32_bf16(Ah[u], Bl, acc2[u][xt], 0, 0, 0);
                acc2[u][xt] = __builtin_amdgcn_mfma_f32_16x16x32_bf16(Al[u], Bh, acc2[u][xt], 0, 0, 0);
            }
        }
    }
    // ---- relu + fc2 partials (lane holds D[m = mb+u*16+lq*4+g][x = xt*16+lr])
    float pj[3][8];
#pragma unroll
    for (int j = 0; j < 3; ++j)
#pragma unroll
        for (int xt = 0; xt < 8; ++xt) pj[j][xt] = 0.f;
#pragma unroll
    for (int u = 0; u < 2; ++u)
#pragma unroll
        for (int g = 0; g < 4; ++g) {
            int m = mb + u * 16 + lq * 4 + g;
            float w20 = w2[m], w21 = w2[NMLP + m], w22 = w2[2 * NMLP + m];
#pragma unroll
            for (int xt = 0; xt < 8; ++xt) {
                float r = fmaxf(acc2[u][xt][g], 0.f);
                pj[0][xt] = fmaf(w20, r, pj[0][xt]);
                pj[1][xt] = fmaf(w21, r, pj[1][xt]);
                pj[2][xt] = fmaf(w22, r, pj[2][xt]);
            }
        }
#pragma unroll
    for (int j = 0; j < 3; ++j)
#pragma unroll
        for (int xt = 0; xt < 8; ++xt) {
            float v = pj[j][xt];
            v += __shfl_xor(v, 16);
            v += __shfl_xor(v, 32);
            pj[j][xt] = v;
        }
    __syncthreads();                    // all cell reads done; reuse smem for partials
    float* part = (float*)smem;         // [4 w][3 j][128 x] = 6 KB
    if (lq == 0) {
#pragma unroll
        for (int j = 0; j < 3; ++j)
#pragma unroll
            for (int xt = 0; xt < 8; ++xt)
                part[(w * 3 + j) * 128 + xt * 16 + lr] = pj[j][xt];
    }
    __syncthreads();
#pragma unroll
    for (int r = 0; r < 2; ++r) {
        int idx = t + r * 256;
        if (idx < 384) {
            int j = idx >> 7, xx = idx & 127;
            float s = b2[j];
#pragma unroll
            for (int ww2 = 0; ww2 < 4; ++ww2) s += part[(ww2 * 3 + j) * 128 + xx];
            out[(size_t)(b * 3 + j) * HW + y * 256 + x0 + xx] = s;
        }
    }
}

extern "C" void kernel_launch(void* const* d_in, const int* in_sizes, int n_in,
                              void* d_out, int out_size, void* d_ws, size_t ws_size,
                              hipStream_t stream) {
    const float* x     = (const float*)d_in[0];
    const float* fc0_w = (const float*)d_in[1];
    const float* fc0_b = (const float*)d_in[2];
    const float* swre  = (const float*)d_in[3];
    const float* swim  = (const float*)d_in[4];
    const float* ww    = (const float*)d_in[5];
    const float* wb    = (const float*)d_in[6];
    const float* fc1w  = (const float*)d_in[7];
    const float* fc1b  = (const float*)d_in[8];
    const float* fc2w  = (const float*)d_in[9];
    const float* fc2b  = (const float*)d_in[10];

    float* ws = (float*)d_ws;
    float2* tab     = (float2*)ws;                    // 512 floats
    ushort* hs_h    = (ushort*)(ws + 512);            // 33.5M u16 (67 MB)
    ushort* hs_l    = (ushort*)(ws + 512 + 16777216); // 33.5M u16 (67 MB)
    float*  T1F     = ws + 33554944;                  // 4,194,304
    float2* X       = (float2*)(ws + 37749248);       // 262,144 floats
    float2* Y       = (float2*)(ws + 38011392);       // 262,144 floats
    float*  Gq      = ws + 38273536;                  // 4,194,304
    float*  trig    = ws + 42467840;                  // 8,192
    uint4*  trigs_h = (uint4*)(ws + 42476032);        // 1024 cells
    uint4*  trigs_l = (uint4*)(ws + 42480128);        // 1024 cells
    uint4*  wws_h   = (uint4*)(ws + 42484224);        // 2048 cells
    uint4*  wws_l   = (uint4*)(ws + 42492416);        // 2048 cells
    uint4*  w1s_h   = (uint4*)(ws + 42500608);        // 1024 cells
    uint4*  w1s_l   = (uint4*)(ws + 42504704);        // 1024 cells
    uint4*  ETh     = (uint4*)(ws + 42508800);        // 1024 cells
    uint4*  ETl     = (uint4*)(ws + 42512896);        // 1024 cells

    k_table<<<dim3(1), dim3(256), 0, stream>>>(tab);
    k_prep0<<<dim3(48), dim3(256), 0, stream>>>(tab, fc1w, ww, trig,
                                                trigs_h, trigs_l, wws_h, wws_l,
                                                w1s_h, w1s_l);
    k_prep_et<<<dim3(4), dim3(256), 0, stream>>>(tab, ETh, ETl);
    k_fc0<<<dim3(256), dim3(256), 0, stream>>>(x, fc0_w, fc0_b, hs_h, hs_l);

    for (int d = 0; d < NDEPTH; ++d) {
        k_fwd_y<<<dim3(1024), dim3(256), 0, stream>>>(hs_h, hs_l, ETh, ETl, T1F);
        k_fwd_x<<<dim3(512), dim3(256), 0, stream>>>(T1F, trig, X);
        k_mix<<<dim3(256), dim3(256), 0, stream>>>(X, swre + (size_t)d * C * C * 256,
                                                   swim + (size_t)d * C * C * 256, Y);
        k_invy<<<dim3(512), dim3(256), 0, stream>>>(Y, tab, Gq);
        if (d < NDEPTH - 1) {
            k_final<<<dim3(4096), dim3(256), 0, stream>>>(hs_h, hs_l, Gq,
                                                          wws_h + (size_t)d * 512,
                                                          wws_l + (size_t)d * 512,
                                                          wb + d * C, trigs_h, trigs_l);
        } else {
            k_final_fc<<<dim3(4096), dim3(256), 0, stream>>>(hs_h, hs_l, Gq,
                                                             wws_h + (size_t)d * 512,
                                                             wws_l + (size_t)d * 512,
                                                             wb + d * C, trigs_h, trigs_l,
                                                             w1s_h, w1s_l, fc1b, fc2w,
                                                             fc2b, (float*)d_out);
        }
    }
}

// Round 8
// 654.726 us; speedup vs baseline: 1.0596x; 1.0176x over previous
//
#include <hip/hip_runtime.h>

#define Hd 256
#define Wd 256
#define HW 65536
#define C 64
#define B 8
#define M 16
#define NDEPTH 4
#define NMLP 128

typedef __attribute__((ext_vector_type(8))) __bf16 bf16x8;
typedef __attribute__((ext_vector_type(4))) float f32x4;

// lgkm-only barrier: ds visibility without draining vmcnt (in-flight prefetch).
__device__ inline void bar_lgkm() {
    asm volatile("s_waitcnt lgkmcnt(0)" ::: "memory");
    __builtin_amdgcn_s_barrier();
}

// split fp32 -> bf16 hi (RNE) + bf16 lo (RNE of residual); pack 8 -> uint4/plane.
__device__ inline void split_pack8(const float* v, uint4& hq, uint4& lq) {
    unsigned hw[4], lw[4];
#pragma unroll
    for (int i = 0; i < 4; ++i) {
        float a = v[2 * i], bb = v[2 * i + 1];
        unsigned ua = __float_as_uint(a);
        unsigned ha = (ua + 0x7fffu + ((ua >> 16) & 1u)) & 0xffff0000u;
        float ra = a - __uint_as_float(ha);
        unsigned ural = __float_as_uint(ra);
        unsigned la = (ural + 0x7fffu + ((ural >> 16) & 1u)) >> 16;
        unsigned ub = __float_as_uint(bb);
        unsigned hb = (ub + 0x7fffu + ((ub >> 16) & 1u)) & 0xffff0000u;
        float rb = bb - __uint_as_float(hb);
        unsigned urbl = __float_as_uint(rb);
        unsigned lb = (urbl + 0x7fffu + ((urbl >> 16) & 1u)) >> 16;
        hw[i] = (ha >> 16) | (hb & 0xffff0000u);
        lw[i] = la | (lb << 16);
    }
    hq = make_uint4(hw[0], hw[1], hw[2], hw[3]);
    lq = make_uint4(lw[0], lw[1], lw[2], lw[3]);
}

// scalar split
__device__ inline void split1(float s, ushort& h, ushort& l) {
    unsigned ua = __float_as_uint(s);
    unsigned ha = (ua + 0x7fffu + ((ua >> 16) & 1u)) & 0xffff0000u;
    float r = s - __uint_as_float(ha);
    unsigned ur = __float_as_uint(r);
    h = (ushort)(ha >> 16);
    l = (ushort)((ur + 0x7fffu + ((ur >> 16) & 1u)) >> 16);
}

// pack 8 zero-extended u16 -> uint4
__device__ inline uint4 pack8(const unsigned* v) {
    uint4 r;
    r.x = v[0] | (v[1] << 16);
    r.y = v[2] | (v[3] << 16);
    r.z = v[4] | (v[5] << 16);
    r.w = v[6] | (v[7] << 16);
    return r;
}

// h storage: planar split-bf16 ushort planes [b][c][y][x] (x contiguous).

// ---------------- twiddle table ----------------
__global__ void k_table(float2* __restrict__ tab) {
    int t = threadIdx.x;
    double a = (6.283185307179586476925286766559 / 256.0) * (double)t;
    tab[t] = make_float2((float)cos(a), (float)sin(a));
}

// ---------------- once: trig + pre-split cells for W-sides ----------------
__global__ void k_prep0(const float2* __restrict__ tab, const float* __restrict__ fc1w,
                        const float* __restrict__ ww, float* __restrict__ trig,
                        uint4* __restrict__ trigs_h, uint4* __restrict__ trigs_l,
                        uint4* __restrict__ wws_h, uint4* __restrict__ wws_l,
                        uint4* __restrict__ w1s_h, uint4* __restrict__ w1s_l) {
    int blk = blockIdx.x, t = threadIdx.x;
    if (blk < 32) {                    // trig[kk][x]: cos kk<16, +sin kk>=16 (fp32, fwd_x)
        int k = blk & 15;
        float2 e = tab[(k * t) & 255];
        trig[blk * 256 + t] = (blk < 16) ? e.x : e.y;
    } else if (blk < 36) {             // trigs cells [kc 4][x 256], k = trig row
        int idx = (blk - 32) * 256 + t;
        int kc = idx >> 8, x = idx & 255;
        float v[8];
#pragma unroll
        for (int j = 0; j < 8; ++j) {
            int row = kc * 8 + j;
            float2 e = tab[((row & 15) * x) & 255];
            v[j] = (row < 16) ? e.x : e.y;
        }
        uint4 hq, lq; split_pack8(v, hq, lq);
        trigs_h[idx] = hq; trigs_l[idx] = lq;
    } else if (blk < 44) {             // wws cells [(d*2+ph)*4+kc][o 64], k = i
        int idx = (blk - 36) * 256 + t;
        int o = idx & 63, kc = (idx >> 6) & 3, ph = (idx >> 8) & 1, d = idx >> 9;
        float v[8];
#pragma unroll
        for (int j = 0; j < 8; ++j)
            v[j] = ww[d * 4096 + o * 64 + ph * 32 + kc * 8 + j];
        uint4 hq, lq; split_pack8(v, hq, lq);
        wws_h[idx] = hq; wws_l[idx] = lq;
    } else {                           // w1s cells [(ph*4+kc)][m 128], k = i
        int idx = (blk - 44) * 256 + t;
        int m = idx & 127, kc = (idx >> 7) & 3, ph = idx >> 9;
        float v[8];
#pragma unroll
        for (int j = 0; j < 8; ++j)
            v[j] = fc1w[m * 64 + ph * 32 + kc * 8 + j];
        uint4 hq, lq; split_pack8(v, hq, lq);
        w1s_h[idx] = hq; w1s_l[idx] = lq;
    }
}

// ---------------- once: split-bf16 A-fragments of the y-DFT matrix ----------------
__global__ void k_prep_et(const float2* __restrict__ tab,
                          uint4* __restrict__ ETh, uint4* __restrict__ ETl) {
    int c = blockIdx.x * 256 + threadIdx.x;
    if (c >= 1024) return;
    int ph = c >> 7, kc = (c >> 5) & 3, m = c & 31;
    float v[8];
#pragma unroll
    for (int j = 0; j < 8; ++j) {
        int y = ph * 32 + kc * 8 + j;
        float2 e = tab[((m & 15) * y) & 255];
        v[j] = (m < 16) ? e.x : -e.y;
    }
    uint4 hq, lq;
    split_pack8(v, hq, lq);
    ETh[c] = hq; ETl[c] = lq;
}

// ---------------- fc0: planar split output, 8 pixels/thread ----------------
__global__ void k_fc0(const float* __restrict__ x, const float* __restrict__ w,
                      const float* __restrict__ bias,
                      ushort* __restrict__ hs_h, ushort* __restrict__ hs_l) {
    int gp = blockIdx.x * 256 + threadIdx.x;   // 65536 groups of 8 pixels
    int b = gp >> 13, pg = gp & 8191;
    int pix0 = pg * 8;
    float xv[3][8];
#pragma unroll
    for (int ch = 0; ch < 3; ++ch) {
        float4 a = *(const float4*)(x + (size_t)(b * 3 + ch) * HW + pix0);
        float4 c4 = *(const float4*)(x + (size_t)(b * 3 + ch) * HW + pix0 + 4);
        xv[ch][0] = a.x; xv[ch][1] = a.y; xv[ch][2] = a.z; xv[ch][3] = a.w;
        xv[ch][4] = c4.x; xv[ch][5] = c4.y; xv[ch][6] = c4.z; xv[ch][7] = c4.w;
    }
    for (int o = 0; o < C; ++o) {
        float w0 = w[o * 3 + 0], w1 = w[o * 3 + 1], w2 = w[o * 3 + 2], bv = bias[o];
        float v[8];
#pragma unroll
        for (int j = 0; j < 8; ++j)
            v[j] = fmaf(w0, xv[0][j], fmaf(w1, xv[1][j], fmaf(w2, xv[2][j], bv)));
        uint4 hq, lq; split_pack8(v, hq, lq);
        *(uint4*)(hs_h + (size_t)(b * 64 + o) * HW + pix0) = hq;
        *(uint4*)(hs_l + (size_t)(b * 64 + o) * HW + pix0) = lq;
    }
}

// ---------------- forward y-DFT: LDS-free split-bf16 MFMA GEMM ----------------
__global__ __launch_bounds__(256, 4)
void k_fwd_y(const ushort* __restrict__ hs_h, const ushort* __restrict__ hs_l,
             const uint4* __restrict__ ETh, const uint4* __restrict__ ETl,
             float* __restrict__ T1F) {
    int blk = blockIdx.x;                  // bc(512) * xh(2), xh fastest
    int xh = blk & 1, bc = blk >> 1;
    int x0 = xh * 128;
    int t = threadIdx.x;
    int w = t >> 6, l = t & 63;            // wave w owns x in [w*32, w*32+32)
    int lr = l & 15, lq = l >> 4;
    const ushort* pH = hs_h + (size_t)bc * HW + x0 + w * 32 + lr;
    const ushort* pL = hs_l + (size_t)bc * HW + x0 + w * 32 + lr;
    f32x4 acc[2][2];
#pragma unroll
    for (int u = 0; u < 2; ++u)
#pragma unroll
        for (int xt = 0; xt < 2; ++xt) {
            acc[u][xt][0] = 0.f; acc[u][xt][1] = 0.f;
            acc[u][xt][2] = 0.f; acc[u][xt][3] = 0.f;
        }
    unsigned h0[2][8], l0[2][8], h1[2][8], l1[2][8];
    auto loadp = [&](unsigned hv[2][8], unsigned lv[2][8], int ph) {
#pragma unroll
        for (int xt = 0; xt < 2; ++xt)
#pragma unroll
            for (int j = 0; j < 8; ++j) {
                int off = (ph * 32 + lq * 8 + j) * 256 + xt * 16;
                hv[xt][j] = pH[off];
                lv[xt][j] = pL[off];
            }
    };
    loadp(h0, l0, 0);
#pragma unroll
    for (int ph = 0; ph < 8; ++ph) {
        unsigned (*ch)[8] = (ph & 1) ? h1 : h0;
        unsigned (*cl)[8] = (ph & 1) ? l1 : l0;
        unsigned (*nh)[8] = (ph & 1) ? h0 : h1;
        unsigned (*nl)[8] = (ph & 1) ? l0 : l1;
        if (ph < 7) loadp(nh, nl, ph + 1);
        bf16x8 Ah[2], Al[2];
#pragma unroll
        for (int u = 0; u < 2; ++u) {
            int ci = ph * 128 + lq * 32 + u * 16 + lr;
            Ah[u] = __builtin_bit_cast(bf16x8, ETh[ci]);
            Al[u] = __builtin_bit_cast(bf16x8, ETl[ci]);
        }
#pragma unroll
        for (int xt = 0; xt < 2; ++xt) {
            bf16x8 Bh = __builtin_bit_cast(bf16x8, pack8(ch[xt]));
            bf16x8 Bl = __builtin_bit_cast(bf16x8, pack8(cl[xt]));
#pragma unroll
            for (int u = 0; u < 2; ++u) {
                acc[u][xt] = __builtin_amdgcn_mfma_f32_16x16x32_bf16(Ah[u], Bh, acc[u][xt], 0, 0, 0);
                acc[u][xt] = __builtin_amdgcn_mfma_f32_16x16x32_bf16(Ah[u], Bl, acc[u][xt], 0, 0, 0);
                acc[u][xt] = __builtin_amdgcn_mfma_f32_16x16x32_bf16(Al[u], Bh, acc[u][xt], 0, 0, 0);
            }
        }
    }
#pragma unroll
    for (int u = 0; u < 2; ++u)
#pragma unroll
        for (int xt = 0; xt < 2; ++xt)
#pragma unroll
            for (int g = 0; g < 4; ++g)
                T1F[(size_t)bc * 8192 + (u * 16 + lq * 4 + g) * 256 + x0 + w * 32 + xt * 16 + lr] =
                    acc[u][xt][g];
}

// ---------------- forward x-DFT (unchanged) ----------------
__global__ __launch_bounds__(256, 2)
void k_fwd_x(const float* __restrict__ T1F, const float* __restrict__ trig,
             float2* __restrict__ X) {
    __shared__ float sT[32 * 260];
    __shared__ float sG[32 * 260];
    int bc = blockIdx.x, t = threadIdx.x;
#pragma unroll
    for (int p = 0; p < 8; ++p) {
        int f = t + p * 256;
        int row = f >> 6, seg = f & 63;
        ((float4*)(sT + row * 260))[seg] = *(const float4*)(T1F + (size_t)bc * 8192 + f * 4);
        ((float4*)(sG + row * 260))[seg] = *(const float4*)(trig + row * 256 + seg * 4);
    }
    __syncthreads();
    int ky = t >> 4, kx = t & 15;
    const float* Tr = sT + ky * 260;
    const float* Ti = sT + (16 + ky) * 260;
    const float* Cs = sG + kx * 260;
    const float* Sn = sG + (16 + kx) * 260;
    float xr0 = 0.f, xi0 = 0.f, xr1 = 0.f, xi1 = 0.f;
    for (int q = 0; q < 64; q += 2) {
        float4 tr = *(const float4*)(Tr + q * 4);
        float4 ti = *(const float4*)(Ti + q * 4);
        float4 cs = *(const float4*)(Cs + q * 4);
        float4 sn = *(const float4*)(Sn + q * 4);
        xr0 = fmaf(tr.x, cs.x, xr0); xr0 = fmaf(ti.x, sn.x, xr0);
        xi0 = fmaf(ti.x, cs.x, xi0); xi0 = fmaf(-tr.x, sn.x, xi0);
        xr0 = fmaf(tr.y, cs.y, xr0); xr0 = fmaf(ti.y, sn.y, xr0);
        xi0 = fmaf(ti.y, cs.y, xi0); xi0 = fmaf(-tr.y, sn.y, xi0);
        xr0 = fmaf(tr.z, cs.z, xr0); xr0 = fmaf(ti.z, sn.z, xr0);
        xi0 = fmaf(ti.z, cs.z, xi0); xi0 = fmaf(-tr.z, sn.z, xi0);
        xr0 = fmaf(tr.w, cs.w, xr0); xr0 = fmaf(ti.w, sn.w, xr0);
        xi0 = fmaf(ti.w, cs.w, xi0); xi0 = fmaf(-tr.w, sn.w, xi0);
        float4 tr1 = *(const float4*)(Tr + q * 4 + 4);
        float4 ti1 = *(const float4*)(Ti + q * 4 + 4);
        float4 cs1 = *(const float4*)(Cs + q * 4 + 4);
        float4 sn1 = *(const float4*)(Sn + q * 4 + 4);
        xr1 = fmaf(tr1.x, cs1.x, xr1); xr1 = fmaf(ti1.x, sn1.x, xr1);
        xi1 = fmaf(ti1.x, cs1.x, xi1); xi1 = fmaf(-tr1.x, sn1.x, xi1);
        xr1 = fmaf(tr1.y, cs1.y, xr1); xr1 = fmaf(ti1.y, sn1.y, xr1);
        xi1 = fmaf(ti1.y, cs1.y, xi1); xi1 = fmaf(-tr1.y, sn1.y, xi1);
        xr1 = fmaf(tr1.z, cs1.z, xr1); xr1 = fmaf(ti1.z, sn1.z, xr1);
        xi1 = fmaf(ti1.z, cs1.z, xi1); xi1 = fmaf(-tr1.z, sn1.z, xi1);
        xr1 = fmaf(tr1.w, cs1.w, xr1); xr1 = fmaf(ti1.w, sn1.w, xr1);
        xi1 = fmaf(ti1.w, cs1.w, xi1); xi1 = fmaf(-tr1.w, sn1.w, xi1);
    }
    X[bc * 256 + t] = make_float2(xr0 + xr1, xi0 + xi1);
}

// ---------------- mode mixing (unchanged) ----------------
__global__ __launch_bounds__(256, 2)
void k_mix(const float2* __restrict__ X, const float* __restrict__ wre,
           const float* __restrict__ wim, float2* __restrict__ Y) {
    int o = blockIdx.x >> 2;
    int bq = blockIdx.x & 3;
    int m = threadIdx.x;
    int b0 = bq * 2, b1 = bq * 2 + 1;
    float yr0 = 0.f, yi0 = 0.f, yr1 = 0.f, yi1 = 0.f;
    for (int i = 0; i < C; ++i) {
        float wr = wre[(i * C + o) * 256 + m];
        float wi = wim[(i * C + o) * 256 + m];
        float2 x0 = X[(b0 * C + i) * 256 + m];
        float2 x1 = X[(b1 * C + i) * 256 + m];
        yr0 = fmaf(x0.x, wr, fmaf(-x0.y, wi, yr0));
        yi0 = fmaf(x0.x, wi, fmaf(x0.y, wr, yi0));
        yr1 = fmaf(x1.x, wr, fmaf(-x1.y, wi, yr1));
        yi1 = fmaf(x1.x, wi, fmaf(x1.y, wr, yi1));
    }
    Y[(b0 * C + o) * 256 + m] = make_float2(yr0, yi0);
    Y[(b1 * C + o) * 256 + m] = make_float2(yr1, yi1);
}

// ---------------- fused inverse-y + Gq production (unchanged) ----------------
__global__ __launch_bounds__(256, 2)
void k_invy(const float2* __restrict__ Y, const float2* __restrict__ tab,
            float* __restrict__ Gq) {
    __shared__ float2 st[256];
    int blk = blockIdx.x;              // 8b x 4pg x 16yt
    int yt = blk & 15, pg = (blk >> 4) & 3, b = blk >> 6;
    int t = threadIdx.x;
    st[t] = tab[t];
    int o = t & 63, kx = pg * 4 + (t >> 6);
    __syncthreads();
    float sc = (kx == 0 ? 1.0f : 2.0f) * (1.0f / 65536.0f);
    float yr[16], yi[16];
    const float2* yp = Y + (size_t)(b * 64 + o) * 256 + kx;
#pragma unroll
    for (int ky = 0; ky < 16; ++ky) {
        float2 v = yp[ky * 16];
        yr[ky] = v.x * sc;
        yi[ky] = v.y * sc;
    }
    int y0 = yt * 16;
    for (int yy = 0; yy < 16; ++yy) {
        int y = y0 + yy;
        float re = 0.f, im = 0.f;
#pragma unroll
        for (int ky = 0; ky < 16; ++ky) {
            float2 e = st[(ky * y) & 255];
            re = fmaf(yr[ky], e.x, re);
            re = fmaf(-yi[ky], e.y, re);
            im = fmaf(yr[ky], e.y, im);
            im = fmaf(yi[ky], e.x, im);
        }
        float* gp = Gq + (size_t)(b * 256 + y) * 32 * 64 + o;
        gp[kx * 64] = re;
        gp[(16 + kx) * 64] = -im;
    }
}

// ---------------- k_final (d<3): R6 structure (staged Gq, 40 KB, 4 blk/CU) +
// swizzled epilogue. R7's 32KB/5-blk + per-lane Gq raised FETCH/WRITE (partial
// L2 writebacks from extra co-residency) and cost +8 µs — reverted.
__global__ __launch_bounds__(256, 4)
void k_final(ushort* __restrict__ hs_h, ushort* __restrict__ hs_l,
             const float* __restrict__ Gq,
             const uint4* __restrict__ wws_h, const uint4* __restrict__ wws_l,
             const float* __restrict__ wb,
             const uint4* __restrict__ trigs_h, const uint4* __restrict__ trigs_l) {
    __shared__ uint4 smem[2560];       // 40 KB unified
    uint4* sH0h = smem;
    uint4* sH0l = smem + 512;
    uint4* sH1h = smem + 1024;
    uint4* sH1l = smem + 1536;
    uint4* sGh  = smem + 2048;
    uint4* sGl  = smem + 2304;
    int blk = blockIdx.x;              // b(8) * y(256) * xq(2), xq fastest
    int xq = blk & 1, y = (blk >> 1) & 255, b = blk >> 9;
    int x0 = xq * 128;
    int t = threadIdx.x;
    int os = t & 63, q = t >> 6;       // Gq staging
    int w = t >> 6, l = t & 63;        // wave w owns o-rows [w*16, w*16+16)
    int lr = l & 15, lq = l >> 4;
    int xs = t & 127, half = t >> 7;   // H staging: x=xs, channels half*16..+15
    f32x4 acc[8];
    {
        int ob = w * 16 + lq * 4;
        f32x4 ini;
        ini[0] = wb[ob]; ini[1] = wb[ob + 1]; ini[2] = wb[ob + 2]; ini[3] = wb[ob + 3];
#pragma unroll
        for (int xt = 0; xt < 8; ++xt) acc[xt] = ini;
    }
    // ---- upfront loads: Gq (staged pattern), A-frags, H ph0 rows
    float gv[8];
    {
        const float* gsrc = Gq + ((size_t)(b * 256 + y) * 32 + q * 8) * 64 + os;
#pragma unroll
        for (int kk = 0; kk < 8; ++kk) gv[kk] = gsrc[kk * 64];
    }
    uint4 A0h = wws_h[lq * 64 + w * 16 + lr];
    uint4 A0l = wws_l[lq * 64 + w * 16 + lr];
    uint4 A1h = wws_h[(4 + lq) * 64 + w * 16 + lr];
    uint4 A1l = wws_l[(4 + lq) * 64 + w * 16 + lr];
    size_t hb0 = (size_t)(b * 64 + half * 16) * HW + y * 256 + x0 + xs;
    unsigned hv[16], lv[16];
#pragma unroll
    for (int j = 0; j < 16; ++j) {
        hv[j] = hs_h[hb0 + (size_t)j * HW];
        lv[j] = hs_l[hb0 + (size_t)j * HW];
    }
    // ---- stage Gq (split) + H ph0 cells
    {
        uint4 ghq, glq; split_pack8(gv, ghq, glq);
        sGh[q * 64 + os] = ghq; sGl[q * 64 + os] = glq;
    }
#pragma unroll
    for (int c2 = 0; c2 < 2; ++c2) {
        int cell = (half * 2 + c2) * 128 + xs;
        sH0h[cell] = pack8(hv + c2 * 8);
        sH0l[cell] = pack8(lv + c2 * 8);
    }
    // ---- issue H phase-1 loads (channels 32 + half*16 + j)
    unsigned hv1[16], lv1[16];
    size_t hb1 = hb0 + (size_t)32 * HW;
#pragma unroll
    for (int j = 0; j < 16; ++j) {
        hv1[j] = hs_h[hb1 + (size_t)j * HW];
        lv1[j] = hs_l[hb1 + (size_t)j * HW];
    }
    bar_lgkm();
    // ---- phase 0 MFMA
#pragma unroll
    for (int xt = 0; xt < 8; ++xt) {
        bf16x8 Bh = __builtin_bit_cast(bf16x8, sH0h[lq * 128 + xt * 16 + lr]);
        bf16x8 Bl = __builtin_bit_cast(bf16x8, sH0l[lq * 128 + xt * 16 + lr]);
        bf16x8 Ah = __builtin_bit_cast(bf16x8, A0h);
        bf16x8 Al = __builtin_bit_cast(bf16x8, A0l);
        acc[xt] = __builtin_amdgcn_mfma_f32_16x16x32_bf16(Ah, Bh, acc[xt], 0, 0, 0);
        acc[xt] = __builtin_amdgcn_mfma_f32_16x16x32_bf16(Ah, Bl, acc[xt], 0, 0, 0);
        acc[xt] = __builtin_amdgcn_mfma_f32_16x16x32_bf16(Al, Bh, acc[xt], 0, 0, 0);
    }
    // ---- stage H ph1 into second buffer
#pragma unroll
    for (int c2 = 0; c2 < 2; ++c2) {
        int cell = (half * 2 + c2) * 128 + xs;
        sH1h[cell] = pack8(hv1 + c2 * 8);
        sH1l[cell] = pack8(lv1 + c2 * 8);
    }
    bar_lgkm();
    // ---- phase 1 MFMA
#pragma unroll
    for (int xt = 0; xt < 8; ++xt) {
        bf16x8 Bh = __builtin_bit_cast(bf16x8, sH1h[lq * 128 + xt * 16 + lr]);
        bf16x8 Bl = __builtin_bit_cast(bf16x8, sH1l[lq * 128 + xt * 16 + lr]);
        bf16x8 Ah = __builtin_bit_cast(bf16x8, A1h);
        bf16x8 Al = __builtin_bit_cast(bf16x8, A1l);
        acc[xt] = __builtin_amdgcn_mfma_f32_16x16x32_bf16(Ah, Bh, acc[xt], 0, 0, 0);
        acc[xt] = __builtin_amdgcn_mfma_f32_16x16x32_bf16(Ah, Bl, acc[xt], 0, 0, 0);
        acc[xt] = __builtin_amdgcn_mfma_f32_16x16x32_bf16(Al, Bh, acc[xt], 0, 0, 0);
    }
    // ---- phase 2 MFMA: A = Gq cells from LDS, B = trigs cells direct
    {
        bf16x8 Ah = __builtin_bit_cast(bf16x8, sGh[lq * 64 + w * 16 + lr]);
        bf16x8 Al = __builtin_bit_cast(bf16x8, sGl[lq * 64 + w * 16 + lr]);
#pragma unroll
        for (int xt = 0; xt < 8; ++xt) {
            bf16x8 Bh = __builtin_bit_cast(bf16x8, trigs_h[lq * 256 + x0 + xt * 16 + lr]);
            bf16x8 Bl = __builtin_bit_cast(bf16x8, trigs_l[lq * 256 + x0 + xt * 16 + lr]);
            acc[xt] = __builtin_amdgcn_mfma_f32_16x16x32_bf16(Ah, Bh, acc[xt], 0, 0, 0);
            acc[xt] = __builtin_amdgcn_mfma_f32_16x16x32_bf16(Ah, Bl, acc[xt], 0, 0, 0);
            acc[xt] = __builtin_amdgcn_mfma_f32_16x16x32_bf16(Al, Bh, acc[xt], 0, 0, 0);
        }
    }
    // ---- epilogue: relu + split into swizzled [64][128] LDS planes, coalesced stores
    __syncthreads();                       // all sH/sG reads done; reuse smem[0..2048)
    ushort* eh = (ushort*)smem;            // [64 o][128 col^swz] hi plane (16 KB)
    ushort* el = (ushort*)(smem + 1024);   // lo plane (16 KB)
    int swz = lq * 40;                     // bank-spread XOR (bits 3..6, 8-aligned)
#pragma unroll
    for (int xt = 0; xt < 8; ++xt)
#pragma unroll
        for (int g = 0; g < 4; ++g) {
            int o = w * 16 + lq * 4 + g;
            float r = fmaxf(acc[xt][g], 0.f);
            ushort hh, ll; split1(r, hh, ll);
            int col = (xt * 16 + lr) ^ swz;
            eh[o * 128 + col] = hh;
            el[o * 128 + col] = ll;
        }
    __syncthreads();
#pragma unroll
    for (int p = 0; p < 4; ++p) {
        int f = t + p * 256;               // o = f>>4, seg = f&15
        int o = f >> 4, seg = f & 15;
        int ko = ((o >> 2) & 3) * 40;      // writer's lq = (o>>2)&3
        int cb = (seg * 8) ^ ko;           // swizzled LDS block holding true cols seg*8..+7
        size_t base = (size_t)(b * 64 + o) * HW + y * 256 + x0;
        *(uint4*)(hs_h + base + seg * 8) = *(uint4*)(eh + o * 128 + cb);
        *(uint4*)(hs_l + base + seg * 8) = *(uint4*)(el + o * 128 + cb);
    }
}

// ---------------- k_final_fc (d=3): k_final + fused fc1/fc2, no h round-trip ----------------
__global__ __launch_bounds__(256, 3)
void k_final_fc(const ushort* __restrict__ hs_h, const ushort* __restrict__ hs_l,
                const float* __restrict__ Gq,
                const uint4* __restrict__ wws_h, const uint4* __restrict__ wws_l,
                const float* __restrict__ wb,
                const uint4* __restrict__ trigs_h, const uint4* __restrict__ trigs_l,
                const uint4* __restrict__ w1s_h, const uint4* __restrict__ w1s_l,
                const float* __restrict__ b1, const float* __restrict__ w2,
                const float* __restrict__ b2, float* __restrict__ out) {
    __shared__ uint4 smem[2048];       // 32 KB unified
    uint4* sH0h = smem;
    uint4* sH0l = smem + 512;
    uint4* sH1h = smem + 1024;
    uint4* sH1l = smem + 1536;
    int blk = blockIdx.x;
    int xq = blk & 1, y = (blk >> 1) & 255, b = blk >> 9;
    int x0 = xq * 128;
    int t = threadIdx.x;
    int w = t >> 6, l = t & 63;
    int lr = l & 15, lq = l >> 4;
    int xs = t & 127, half = t >> 7;
    f32x4 acc[8];
    {
        int ob = w * 16 + lq * 4;
        f32x4 ini;
        ini[0] = wb[ob]; ini[1] = wb[ob + 1]; ini[2] = wb[ob + 2]; ini[3] = wb[ob + 3];
#pragma unroll
        for (int xt = 0; xt < 8; ++xt) acc[xt] = ini;
    }
    float gv[8];
    {
        const float* gsrc = Gq + ((size_t)(b * 256 + y) * 32 + lq * 8) * 64 + w * 16 + lr;
#pragma unroll
        for (int kk = 0; kk < 8; ++kk) gv[kk] = gsrc[kk * 64];
    }
    uint4 A0h = wws_h[lq * 64 + w * 16 + lr];
    uint4 A0l = wws_l[lq * 64 + w * 16 + lr];
    uint4 A1h = wws_h[(4 + lq) * 64 + w * 16 + lr];
    uint4 A1l = wws_l[(4 + lq) * 64 + w * 16 + lr];
    size_t hb0 = (size_t)(b * 64 + half * 16) * HW + y * 256 + x0 + xs;
    unsigned hv[16], lv[16];
#pragma unroll
    for (int j = 0; j < 16; ++j) {
        hv[j] = hs_h[hb0 + (size_t)j * HW];
        lv[j] = hs_l[hb0 + (size_t)j * HW];
    }
#pragma unroll
    for (int c2 = 0; c2 < 2; ++c2) {
        int cell = (half * 2 + c2) * 128 + xs;
        sH0h[cell] = pack8(hv + c2 * 8);
        sH0l[cell] = pack8(lv + c2 * 8);
    }
    unsigned hv1[16], lv1[16];
    size_t hb1 = hb0 + (size_t)32 * HW;
#pragma unroll
    for (int j = 0; j < 16; ++j) {
        hv1[j] = hs_h[hb1 + (size_t)j * HW];
        lv1[j] = hs_l[hb1 + (size_t)j * HW];
    }
    bar_lgkm();
#pragma unroll
    for (int xt = 0; xt < 8; ++xt) {
        bf16x8 Bh = __builtin_bit_cast(bf16x8, sH0h[lq * 128 + xt * 16 + lr]);
        bf16x8 Bl = __builtin_bit_cast(bf16x8, sH0l[lq * 128 + xt * 16 + lr]);
        bf16x8 Ah = __builtin_bit_cast(bf16x8, A0h);
        bf16x8 Al = __builtin_bit_cast(bf16x8, A0l);
        acc[xt] = __builtin_amdgcn_mfma_f32_16x16x32_bf16(Ah, Bh, acc[xt], 0, 0, 0);
        acc[xt] = __builtin_amdgcn_mfma_f32_16x16x32_bf16(Ah, Bl, acc[xt], 0, 0, 0);
        acc[xt] = __builtin_amdgcn_mfma_f32_16x16x32_bf16(Al, Bh, acc[xt], 0, 0, 0);
    }
#pragma unroll
    for (int c2 = 0; c2 < 2; ++c2) {
        int cell = (half * 2 + c2) * 128 + xs;
        sH1h[cell] = pack8(hv1 + c2 * 8);
        sH1l[cell] = pack8(lv1 + c2 * 8);
    }
    bar_lgkm();
#pragma unroll
    for (int xt = 0; xt < 8; ++xt) {
        bf16x8 Bh = __builtin_bit_cast(bf16x8, sH1h[lq * 128 + xt * 16 + lr]);
        bf16x8 Bl = __builtin_bit_cast(bf16x8, sH1l[lq * 128 + xt * 16 + lr]);
        bf16x8 Ah = __builtin_bit_cast(bf16x8, A1h);
        bf16x8 Al = __builtin_bit_cast(bf16x8, A1l);
        acc[xt] = __builtin_amdgcn_mfma_f32_16x16x32_bf16(Ah, Bh, acc[xt], 0, 0, 0);
        acc[xt] = __builtin_amdgcn_mfma_f32_16x16x32_bf16(Ah, Bl, acc[xt], 0, 0, 0);
        acc[xt] = __builtin_amdgcn_mfma_f32_16x16x32_bf16(Al, Bh, acc[xt], 0, 0, 0);
    }
    {
        uint4 gh4, gl4; split_pack8(gv, gh4, gl4);
        bf16x8 Ah = __builtin_bit_cast(bf16x8, gh4);
        bf16x8 Al = __builtin_bit_cast(bf16x8, gl4);
#pragma unroll
        for (int xt = 0; xt < 8; ++xt) {
            bf16x8 Bh = __builtin_bit_cast(bf16x8, trigs_h[lq * 256 + x0 + xt * 16 + lr]);
            bf16x8 Bl = __builtin_bit_cast(bf16x8, trigs_l[lq * 256 + x0 + xt * 16 + lr]);
            acc[xt] = __builtin_amdgcn_mfma_f32_16x16x32_bf16(Ah, Bh, acc[xt], 0, 0, 0);
            acc[xt] = __builtin_amdgcn_mfma_f32_16x16x32_bf16(Ah, Bl, acc[xt], 0, 0, 0);
            acc[xt] = __builtin_amdgcn_mfma_f32_16x16x32_bf16(Al, Bh, acc[xt], 0, 0, 0);
        }
    }
    // ---- h_new (relu, split) into LDS cells [kc 8][x 128][8k] per plane
    __syncthreads();
    ushort* ch16 = (ushort*)smem;              // hi cells (16 KB)
    ushort* cl16 = (ushort*)(smem + 1024);     // lo cells (16 KB)
#pragma unroll
    for (int xt = 0; xt < 8; ++xt)
#pragma unroll
        for (int g = 0; g < 4; ++g) {
            int o = w * 16 + lq * 4 + g;
            float r = fmaxf(acc[xt][g], 0.f);
            ushort hh, ll; split1(r, hh, ll);
            int ci = ((o >> 3) * 128 + xt * 16 + lr) * 8 + (o & 7);
            ch16[ci] = hh;
            cl16[ci] = ll;
        }
    __syncthreads();
    // ---- fc1 GEMM from LDS cells (K=64, 2 phases), A = w1s
    uint4* cells_h = smem;
    uint4* cells_l = smem + 1024;
    int mb = w * 32;
    f32x4 acc2[2][8];
#pragma unroll
    for (int u = 0; u < 2; ++u) {
        int m0 = mb + u * 16 + lq * 4;
        f32x4 ini;
        ini[0] = b1[m0]; ini[1] = b1[m0 + 1]; ini[2] = b1[m0 + 2]; ini[3] = b1[m0 + 3];
#pragma unroll
        for (int xt = 0; xt < 8; ++xt) acc2[u][xt] = ini;
    }
#pragma unroll
    for (int ph = 0; ph < 2; ++ph) {
        bf16x8 Ah[2], Al[2];
#pragma unroll
        for (int u = 0; u < 2; ++u) {
            Ah[u] = __builtin_bit_cast(bf16x8, w1s_h[(ph * 4 + lq) * 128 + mb + u * 16 + lr]);
            Al[u] = __builtin_bit_cast(bf16x8, w1s_l[(ph * 4 + lq) * 128 + mb + u * 16 + lr]);
        }
#pragma unroll
        for (int xt = 0; xt < 8; ++xt) {
            bf16x8 Bh = __builtin_bit_cast(bf16x8, cells_h[(ph * 4 + lq) * 128 + xt * 16 + lr]);
            bf16x8 Bl = __builtin_bit_cast(bf16x8, cells_l[(ph * 4 + lq) * 128 + xt * 16 + lr]);
#pragma unroll
            for (int u = 0; u < 2; ++u) {
                acc2[u][xt] = __builtin_amdgcn_mfma_f32_16x16x32_bf16(Ah[u], Bh, acc2[u][xt], 0, 0, 0);
                acc2[u][xt] = __builtin_amdgcn_mfma_f32_16x16x32_bf16(Ah[u], Bl, acc2[u][xt], 0, 0, 0);
                acc2[u][xt] = __builtin_amdgcn_mfma_f32_16x16x32_bf16(Al[u], Bh, acc2[u][xt], 0, 0, 0);
            }
        }
    }
    // ---- relu + fc2 partials (lane holds D[m = mb+u*16+lq*4+g][x = xt*16+lr])
    float pj[3][8];
#pragma unroll
    for (int j = 0; j < 3; ++j)
#pragma unroll
        for (int xt = 0; xt < 8; ++xt) pj[j][xt] = 0.f;
#pragma unroll
    for (int u = 0; u < 2; ++u)
#pragma unroll
        for (int g = 0; g < 4; ++g) {
            int m = mb + u * 16 + lq * 4 + g;
            float w20 = w2[m], w21 = w2[NMLP + m], w22 = w2[2 * NMLP + m];
#pragma unroll
            for (int xt = 0; xt < 8; ++xt) {
                float r = fmaxf(acc2[u][xt][g], 0.f);
                pj[0][xt] = fmaf(w20, r, pj[0][xt]);
                pj[1][xt] = fmaf(w21, r, pj[1][xt]);
                pj[2][xt] = fmaf(w22, r, pj[2][xt]);
            }
        }
#pragma unroll
    for (int j = 0; j < 3; ++j)
#pragma unroll
        for (int xt = 0; xt < 8; ++xt) {
            float v = pj[j][xt];
            v += __shfl_xor(v, 16);
            v += __shfl_xor(v, 32);
            pj[j][xt] = v;
        }
    __syncthreads();                    // all cell reads done; reuse smem for partials
    float* part = (float*)smem;         // [4 w][3 j][128 x] = 6 KB
    if (lq == 0) {
#pragma unroll
        for (int j = 0; j < 3; ++j)
#pragma unroll
            for (int xt = 0; xt < 8; ++xt)
                part[(w * 3 + j) * 128 + xt * 16 + lr] = pj[j][xt];
    }
    __syncthreads();
#pragma unroll
    for (int r = 0; r < 2; ++r) {
        int idx = t + r * 256;
        if (idx < 384) {
            int j = idx >> 7, xx = idx & 127;
            float s = b2[j];
#pragma unroll
            for (int ww2 = 0; ww2 < 4; ++ww2) s += part[(ww2 * 3 + j) * 128 + xx];
            out[(size_t)(b * 3 + j) * HW + y * 256 + x0 + xx] = s;
        }
    }
}

extern "C" void kernel_launch(void* const* d_in, const int* in_sizes, int n_in,
                              void* d_out, int out_size, void* d_ws, size_t ws_size,
                              hipStream_t stream) {
    const float* x     = (const float*)d_in[0];
    const float* fc0_w = (const float*)d_in[1];
    const float* fc0_b = (const float*)d_in[2];
    const float* swre  = (const float*)d_in[3];
    const float* swim  = (const float*)d_in[4];
    const float* ww    = (const float*)d_in[5];
    const float* wb    = (const float*)d_in[6];
    const float* fc1w  = (const float*)d_in[7];
    const float* fc1b  = (const float*)d_in[8];
    const float* fc2w  = (const float*)d_in[9];
    const float* fc2b  = (const float*)d_in[10];

    float* ws = (float*)d_ws;
    float2* tab     = (float2*)ws;                    // 512 floats
    ushort* hs_h    = (ushort*)(ws + 512);            // 33.5M u16 (67 MB)
    ushort* hs_l    = (ushort*)(ws + 512 + 16777216); // 33.5M u16 (67 MB)
    float*  T1F     = ws + 33554944;                  // 4,194,304
    float2* X       = (float2*)(ws + 37749248);       // 262,144 floats
    float2* Y       = (float2*)(ws + 38011392);       // 262,144 floats
    float*  Gq      = ws + 38273536;                  // 4,194,304
    float*  trig    = ws + 42467840;                  // 8,192
    uint4*  trigs_h = (uint4*)(ws + 42476032);        // 1024 cells
    uint4*  trigs_l = (uint4*)(ws + 42480128);        // 1024 cells
    uint4*  wws_h   = (uint4*)(ws + 42484224);        // 2048 cells
    uint4*  wws_l   = (uint4*)(ws + 42492416);        // 2048 cells
    uint4*  w1s_h   = (uint4*)(ws + 42500608);        // 1024 cells
    uint4*  w1s_l   = (uint4*)(ws + 42504704);        // 1024 cells
    uint4*  ETh     = (uint4*)(ws + 42508800);        // 1024 cells
    uint4*  ETl     = (uint4*)(ws + 42512896);        // 1024 cells

    k_table<<<dim3(1), dim3(256), 0, stream>>>(tab);
    k_prep0<<<dim3(48), dim3(256), 0, stream>>>(tab, fc1w, ww, trig,
                                                trigs_h, trigs_l, wws_h, wws_l,
                                                w1s_h, w1s_l);
    k_prep_et<<<dim3(4), dim3(256), 0, stream>>>(tab, ETh, ETl);
    k_fc0<<<dim3(256), dim3(256), 0, stream>>>(x, fc0_w, fc0_b, hs_h, hs_l);

    for (int d = 0; d < NDEPTH; ++d) {
        k_fwd_y<<<dim3(1024), dim3(256), 0, stream>>>(hs_h, hs_l, ETh, ETl, T1F);
        k_fwd_x<<<dim3(512), dim3(256), 0, stream>>>(T1F, trig, X);
        k_mix<<<dim3(256), dim3(256), 0, stream>>>(X, swre + (size_t)d * C * C * 256,
                                                   swim + (size_t)d * C * C * 256, Y);
        k_invy<<<dim3(512), dim3(256), 0, stream>>>(Y, tab, Gq);
        if (d < NDEPTH - 1) {
            k_final<<<dim3(4096), dim3(256), 0, stream>>>(hs_h, hs_l, Gq,
                                                          wws_h + (size_t)d * 512,
                                                          wws_l + (size_t)d * 512,
                                                          wb + d * C, trigs_h, trigs_l);
        } else {
            k_final_fc<<<dim3(4096), dim3(256), 0, stream>>>(hs_h, hs_l, Gq,
                                                             wws_h + (size_t)d * 512,
                                                             wws_l + (size_t)d * 512,
                                                             wb + d * C, trigs_h, trigs_l,
                                                             w1s_h, w1s_l, fc1b, fc2w,
                                                             fc2b, (float*)d_out);
        }
    }
}

// Round 9
// 628.232 us; speedup vs baseline: 1.1043x; 1.0422x over previous
//
#include <hip/hip_runtime.h>

#define Hd 256
#define Wd 256
#define HW 65536
#define C 64
#define B 8
#define M 16
#define NDEPTH 4
#define NMLP 128

typedef __attribute__((ext_vector_type(8))) __bf16 bf16x8;
typedef __attribute__((ext_vector_type(4))) float f32x4;

// lgkm-only barrier: ds visibility without draining vmcnt (in-flight prefetch).
__device__ inline void bar_lgkm() {
    asm volatile("s_waitcnt lgkmcnt(0)" ::: "memory");
    __builtin_amdgcn_s_barrier();
}

// split fp32 -> bf16 hi (RNE) + bf16 lo (RNE of residual); pack 8 -> uint4/plane.
__device__ inline void split_pack8(const float* v, uint4& hq, uint4& lq) {
    unsigned hw[4], lw[4];
#pragma unroll
    for (int i = 0; i < 4; ++i) {
        float a = v[2 * i], bb = v[2 * i + 1];
        unsigned ua = __float_as_uint(a);
        unsigned ha = (ua + 0x7fffu + ((ua >> 16) & 1u)) & 0xffff0000u;
        float ra = a - __uint_as_float(ha);
        unsigned ural = __float_as_uint(ra);
        unsigned la = (ural + 0x7fffu + ((ural >> 16) & 1u)) >> 16;
        unsigned ub = __float_as_uint(bb);
        unsigned hb = (ub + 0x7fffu + ((ub >> 16) & 1u)) & 0xffff0000u;
        float rb = bb - __uint_as_float(hb);
        unsigned urbl = __float_as_uint(rb);
        unsigned lb = (urbl + 0x7fffu + ((urbl >> 16) & 1u)) >> 16;
        hw[i] = (ha >> 16) | (hb & 0xffff0000u);
        lw[i] = la | (lb << 16);
    }
    hq = make_uint4(hw[0], hw[1], hw[2], hw[3]);
    lq = make_uint4(lw[0], lw[1], lw[2], lw[3]);
}

// scalar split
__device__ inline void split1(float s, ushort& h, ushort& l) {
    unsigned ua = __float_as_uint(s);
    unsigned ha = (ua + 0x7fffu + ((ua >> 16) & 1u)) & 0xffff0000u;
    float r = s - __uint_as_float(ha);
    unsigned ur = __float_as_uint(r);
    h = (ushort)(ha >> 16);
    l = (ushort)((ur + 0x7fffu + ((ur >> 16) & 1u)) >> 16);
}

// pack 8 zero-extended u16 -> uint4
__device__ inline uint4 pack8(const unsigned* v) {
    uint4 r;
    r.x = v[0] | (v[1] << 16);
    r.y = v[2] | (v[3] << 16);
    r.z = v[4] | (v[5] << 16);
    r.w = v[6] | (v[7] << 16);
    return r;
}

// h storage: planar split-bf16 ushort planes [b][c][y][x] (x contiguous).
// T1F storage: planar split-bf16 ushort planes [bc][32 kk][256 x].

// ---------------- twiddle table ----------------
__global__ void k_table(float2* __restrict__ tab) {
    int t = threadIdx.x;
    double a = (6.283185307179586476925286766559 / 256.0) * (double)t;
    tab[t] = make_float2((float)cos(a), (float)sin(a));
}

// ---------------- once: pre-split cells for W-sides ----------------
__global__ void k_prep0(const float2* __restrict__ tab, const float* __restrict__ fc1w,
                        const float* __restrict__ ww, float* __restrict__ trig,
                        uint4* __restrict__ trigs_h, uint4* __restrict__ trigs_l,
                        uint4* __restrict__ wws_h, uint4* __restrict__ wws_l,
                        uint4* __restrict__ w1s_h, uint4* __restrict__ w1s_l) {
    int blk = blockIdx.x, t = threadIdx.x;
    if (blk < 32) {                    // trig[kk][x] (kept; cheap)
        int k = blk & 15;
        float2 e = tab[(k * t) & 255];
        trig[blk * 256 + t] = (blk < 16) ? e.x : e.y;
    } else if (blk < 36) {             // trigs cells [kc 4][x 256], k = trig row
        int idx = (blk - 32) * 256 + t;
        int kc = idx >> 8, x = idx & 255;
        float v[8];
#pragma unroll
        for (int j = 0; j < 8; ++j) {
            int row = kc * 8 + j;
            float2 e = tab[((row & 15) * x) & 255];
            v[j] = (row < 16) ? e.x : e.y;
        }
        uint4 hq, lq; split_pack8(v, hq, lq);
        trigs_h[idx] = hq; trigs_l[idx] = lq;
    } else if (blk < 44) {             // wws cells [(d*2+ph)*4+kc][o 64], k = i
        int idx = (blk - 36) * 256 + t;
        int o = idx & 63, kc = (idx >> 6) & 3, ph = (idx >> 8) & 1, d = idx >> 9;
        float v[8];
#pragma unroll
        for (int j = 0; j < 8; ++j)
            v[j] = ww[d * 4096 + o * 64 + ph * 32 + kc * 8 + j];
        uint4 hq, lq; split_pack8(v, hq, lq);
        wws_h[idx] = hq; wws_l[idx] = lq;
    } else {                           // w1s cells [(ph*4+kc)][m 128], k = i
        int idx = (blk - 44) * 256 + t;
        int m = idx & 127, kc = (idx >> 7) & 3, ph = idx >> 9;
        float v[8];
#pragma unroll
        for (int j = 0; j < 8; ++j)
            v[j] = fc1w[m * 64 + ph * 32 + kc * 8 + j];
        uint4 hq, lq; split_pack8(v, hq, lq);
        w1s_h[idx] = hq; w1s_l[idx] = lq;
    }
}

// ---------------- once: split-bf16 fragments for y-DFT (ET) and x-DFT (TX) ----------------
__global__ void k_prep_et(const float2* __restrict__ tab,
                          uint4* __restrict__ ETh, uint4* __restrict__ ETl,
                          uint4* __restrict__ TXh, uint4* __restrict__ TXl) {
    int c = blockIdx.x * 256 + threadIdx.x;
    if (c < 1024) {
        int ph = c >> 7, kc = (c >> 5) & 3, m = c & 31;
        float v[8];
#pragma unroll
        for (int j = 0; j < 8; ++j) {
            int y = ph * 32 + kc * 8 + j;
            float2 e = tab[((m & 15) * y) & 255];
            v[j] = (m < 16) ? e.x : -e.y;
        }
        uint4 hq, lq; split_pack8(v, hq, lq);
        ETh[c] = hq; ETl[c] = lq;
    } else if (c < 2048) {
        // TX cells [kcq 32][km 32]: x = kcq*8+j; km<16: cos(km x), km>=16: sin((km-16) x)
        int cc = c - 1024;
        int kcq = cc >> 5, km = cc & 31;
        float v[8];
#pragma unroll
        for (int j = 0; j < 8; ++j) {
            int x = kcq * 8 + j;
            float2 e = tab[((km & 15) * x) & 255];
            v[j] = (km < 16) ? e.x : e.y;
        }
        uint4 hq, lq; split_pack8(v, hq, lq);
        TXh[cc] = hq; TXl[cc] = lq;
    }
}

// ---------------- fc0: planar split output, 8 pixels/thread ----------------
__global__ void k_fc0(const float* __restrict__ x, const float* __restrict__ w,
                      const float* __restrict__ bias,
                      ushort* __restrict__ hs_h, ushort* __restrict__ hs_l) {
    int gp = blockIdx.x * 256 + threadIdx.x;   // 65536 groups of 8 pixels
    int b = gp >> 13, pg = gp & 8191;
    int pix0 = pg * 8;
    float xv[3][8];
#pragma unroll
    for (int ch = 0; ch < 3; ++ch) {
        float4 a = *(const float4*)(x + (size_t)(b * 3 + ch) * HW + pix0);
        float4 c4 = *(const float4*)(x + (size_t)(b * 3 + ch) * HW + pix0 + 4);
        xv[ch][0] = a.x; xv[ch][1] = a.y; xv[ch][2] = a.z; xv[ch][3] = a.w;
        xv[ch][4] = c4.x; xv[ch][5] = c4.y; xv[ch][6] = c4.z; xv[ch][7] = c4.w;
    }
    for (int o = 0; o < C; ++o) {
        float w0 = w[o * 3 + 0], w1 = w[o * 3 + 1], w2 = w[o * 3 + 2], bv = bias[o];
        float v[8];
#pragma unroll
        for (int j = 0; j < 8; ++j)
            v[j] = fmaf(w0, xv[0][j], fmaf(w1, xv[1][j], fmaf(w2, xv[2][j], bv)));
        uint4 hq, lq; split_pack8(v, hq, lq);
        *(uint4*)(hs_h + (size_t)(b * 64 + o) * HW + pix0) = hq;
        *(uint4*)(hs_l + (size_t)(b * 64 + o) * HW + pix0) = lq;
    }
}

// ---------------- forward y-DFT: LDS-free MFMA GEMM + split T1F epilogue ----------------
// R22: epilogue now writes T1F as split-bf16 planes (via the proven swz=lq*40
// LDS transpose) so fwd_x can MFMA with single-uint4 A-fragments (x contiguous).
__global__ __launch_bounds__(256, 4)
void k_fwd_y(const ushort* __restrict__ hs_h, const ushort* __restrict__ hs_l,
             const uint4* __restrict__ ETh, const uint4* __restrict__ ETl,
             ushort* __restrict__ T1Fs_h, ushort* __restrict__ T1Fs_l) {
    __shared__ ushort eh[32 * 128], el[32 * 128];   // 8 + 8 KB
    int blk = blockIdx.x;                  // bc(512) * xh(2), xh fastest
    int xh = blk & 1, bc = blk >> 1;
    int x0 = xh * 128;
    int t = threadIdx.x;
    int w = t >> 6, l = t & 63;            // wave w owns x in [w*32, w*32+32)
    int lr = l & 15, lq = l >> 4;
    const ushort* pH = hs_h + (size_t)bc * HW + x0 + w * 32 + lr;
    const ushort* pL = hs_l + (size_t)bc * HW + x0 + w * 32 + lr;
    f32x4 acc[2][2];
#pragma unroll
    for (int u = 0; u < 2; ++u)
#pragma unroll
        for (int xt = 0; xt < 2; ++xt) {
            acc[u][xt][0] = 0.f; acc[u][xt][1] = 0.f;
            acc[u][xt][2] = 0.f; acc[u][xt][3] = 0.f;
        }
    unsigned h0[2][8], l0[2][8], h1[2][8], l1[2][8];
    auto loadp = [&](unsigned hv[2][8], unsigned lv[2][8], int ph) {
#pragma unroll
        for (int xt = 0; xt < 2; ++xt)
#pragma unroll
            for (int j = 0; j < 8; ++j) {
                int off = (ph * 32 + lq * 8 + j) * 256 + xt * 16;
                hv[xt][j] = pH[off];
                lv[xt][j] = pL[off];
            }
    };
    loadp(h0, l0, 0);
#pragma unroll
    for (int ph = 0; ph < 8; ++ph) {
        unsigned (*ch)[8] = (ph & 1) ? h1 : h0;
        unsigned (*cl)[8] = (ph & 1) ? l1 : l0;
        unsigned (*nh)[8] = (ph & 1) ? h0 : h1;
        unsigned (*nl)[8] = (ph & 1) ? l0 : l1;
        if (ph < 7) loadp(nh, nl, ph + 1);
        bf16x8 Ah[2], Al[2];
#pragma unroll
        for (int u = 0; u < 2; ++u) {
            int ci = ph * 128 + lq * 32 + u * 16 + lr;
            Ah[u] = __builtin_bit_cast(bf16x8, ETh[ci]);
            Al[u] = __builtin_bit_cast(bf16x8, ETl[ci]);
        }
#pragma unroll
        for (int xt = 0; xt < 2; ++xt) {
            bf16x8 Bh = __builtin_bit_cast(bf16x8, pack8(ch[xt]));
            bf16x8 Bl = __builtin_bit_cast(bf16x8, pack8(cl[xt]));
#pragma unroll
            for (int u = 0; u < 2; ++u) {
                acc[u][xt] = __builtin_amdgcn_mfma_f32_16x16x32_bf16(Ah[u], Bh, acc[u][xt], 0, 0, 0);
                acc[u][xt] = __builtin_amdgcn_mfma_f32_16x16x32_bf16(Ah[u], Bl, acc[u][xt], 0, 0, 0);
                acc[u][xt] = __builtin_amdgcn_mfma_f32_16x16x32_bf16(Al[u], Bh, acc[u][xt], 0, 0, 0);
            }
        }
    }
    // epilogue: split + swizzled LDS transpose, coalesced uint4 plane stores
    int swz = lq * 40;
#pragma unroll
    for (int u = 0; u < 2; ++u)
#pragma unroll
        for (int xt = 0; xt < 2; ++xt)
#pragma unroll
            for (int g = 0; g < 4; ++g) {
                int row = u * 16 + lq * 4 + g;
                int col = (w * 32 + xt * 16 + lr) ^ swz;
                ushort hh, ll; split1(acc[u][xt][g], hh, ll);
                eh[row * 128 + col] = hh;
                el[row * 128 + col] = ll;
            }
    __syncthreads();
#pragma unroll
    for (int p = 0; p < 2; ++p) {
        int f = t + p * 256;               // [0,512): row = f>>4, seg = f&15
        int row = f >> 4, seg = f & 15;
        int cb = (seg * 8) ^ (((row >> 2) & 3) * 40);
        size_t dst = (size_t)bc * 8192 + row * 256 + x0 + seg * 8;
        *(uint4*)(T1Fs_h + dst) = *(uint4*)(eh + row * 128 + cb);
        *(uint4*)(T1Fs_l + dst) = *(uint4*)(el + row * 128 + cb);
    }
}

// ---------------- forward x-DFT: split-bf16 MFMA (R22, replaces fp32 VALU) ----------------
// Per bc: D[32 kk][32 km] = T1F[32][256] x TX[256][32] (km<16 cos, km>=16 sin).
// Wave (u,v) owns tile rows u*16.., cols v*16... A-frag = single uint4 from split
// T1F planes (x contiguous); B = prebuilt TX cells. Combine re/im via 4 KB sD.
__global__ __launch_bounds__(256, 8)
void k_fwd_x2(const ushort* __restrict__ T1Fs_h, const ushort* __restrict__ T1Fs_l,
              const uint4* __restrict__ TXh, const uint4* __restrict__ TXl,
              float2* __restrict__ X) {
    __shared__ float sD[32 * 33];
    int bc = blockIdx.x;
    int t = threadIdx.x;
    int w = t >> 6, l = t & 63;
    int lr = l & 15, lq = l >> 4;
    int u = w >> 1, v = w & 1;
    f32x4 acc;
    acc[0] = 0.f; acc[1] = 0.f; acc[2] = 0.f; acc[3] = 0.f;
    const uint4* Ah4 = (const uint4*)T1Fs_h + ((size_t)bc * 32 + u * 16 + lr) * 32 + lq;
    const uint4* Al4 = (const uint4*)T1Fs_l + ((size_t)bc * 32 + u * 16 + lr) * 32 + lq;
    const uint4* Bh4 = TXh + lq * 32 + v * 16 + lr;
    const uint4* Bl4 = TXl + lq * 32 + v * 16 + lr;
#pragma unroll
    for (int ph = 0; ph < 8; ++ph) {
        bf16x8 Ah = __builtin_bit_cast(bf16x8, Ah4[ph * 4]);
        bf16x8 Al = __builtin_bit_cast(bf16x8, Al4[ph * 4]);
        bf16x8 Bh = __builtin_bit_cast(bf16x8, Bh4[ph * 128]);
        bf16x8 Bl = __builtin_bit_cast(bf16x8, Bl4[ph * 128]);
        acc = __builtin_amdgcn_mfma_f32_16x16x32_bf16(Ah, Bh, acc, 0, 0, 0);
        acc = __builtin_amdgcn_mfma_f32_16x16x32_bf16(Ah, Bl, acc, 0, 0, 0);
        acc = __builtin_amdgcn_mfma_f32_16x16x32_bf16(Al, Bh, acc, 0, 0, 0);
    }
    // D[u*16 + lq*4 + g][v*16 + lr]
#pragma unroll
    for (int g = 0; g < 4; ++g)
        sD[(u * 16 + lq * 4 + g) * 33 + v * 16 + lr] = acc[g];
    __syncthreads();
    int ky = t >> 4, kx = t & 15;
    float xr = sD[ky * 33 + kx] + sD[(16 + ky) * 33 + 16 + kx];
    float xi = sD[(16 + ky) * 33 + kx] - sD[ky * 33 + 16 + kx];
    X[(size_t)bc * 256 + t] = make_float2(xr, xi);
}

// ---------------- mode mixing (unchanged) ----------------
__global__ __launch_bounds__(256, 2)
void k_mix(const float2* __restrict__ X, const float* __restrict__ wre,
           const float* __restrict__ wim, float2* __restrict__ Y) {
    int o = blockIdx.x >> 2;
    int bq = blockIdx.x & 3;
    int m = threadIdx.x;
    int b0 = bq * 2, b1 = bq * 2 + 1;
    float yr0 = 0.f, yi0 = 0.f, yr1 = 0.f, yi1 = 0.f;
    for (int i = 0; i < C; ++i) {
        float wr = wre[(i * C + o) * 256 + m];
        float wi = wim[(i * C + o) * 256 + m];
        float2 x0 = X[(b0 * C + i) * 256 + m];
        float2 x1 = X[(b1 * C + i) * 256 + m];
        yr0 = fmaf(x0.x, wr, fmaf(-x0.y, wi, yr0));
        yi0 = fmaf(x0.x, wi, fmaf(x0.y, wr, yi0));
        yr1 = fmaf(x1.x, wr, fmaf(-x1.y, wi, yr1));
        yi1 = fmaf(x1.x, wi, fmaf(x1.y, wr, yi1));
    }
    Y[(b0 * C + o) * 256 + m] = make_float2(yr0, yi0);
    Y[(b1 * C + o) * 256 + m] = make_float2(yr1, yi1);
}

// ---------------- fused inverse-y + Gq production (unchanged) ----------------
__global__ __launch_bounds__(256, 2)
void k_invy(const float2* __restrict__ Y, const float2* __restrict__ tab,
            float* __restrict__ Gq) {
    __shared__ float2 st[256];
    int blk = blockIdx.x;              // 8b x 4pg x 16yt
    int yt = blk & 15, pg = (blk >> 4) & 3, b = blk >> 6;
    int t = threadIdx.x;
    st[t] = tab[t];
    int o = t & 63, kx = pg * 4 + (t >> 6);
    __syncthreads();
    float sc = (kx == 0 ? 1.0f : 2.0f) * (1.0f / 65536.0f);
    float yr[16], yi[16];
    const float2* yp = Y + (size_t)(b * 64 + o) * 256 + kx;
#pragma unroll
    for (int ky = 0; ky < 16; ++ky) {
        float2 v = yp[ky * 16];
        yr[ky] = v.x * sc;
        yi[ky] = v.y * sc;
    }
    int y0 = yt * 16;
    for (int yy = 0; yy < 16; ++yy) {
        int y = y0 + yy;
        float re = 0.f, im = 0.f;
#pragma unroll
        for (int ky = 0; ky < 16; ++ky) {
            float2 e = st[(ky * y) & 255];
            re = fmaf(yr[ky], e.x, re);
            re = fmaf(-yi[ky], e.y, re);
            im = fmaf(yr[ky], e.y, im);
            im = fmaf(yi[ky], e.x, im);
        }
        float* gp = Gq + (size_t)(b * 256 + y) * 32 * 64 + o;
        gp[kx * 64] = re;
        gp[(16 + kx) * 64] = -im;
    }
}

// ---------------- k_final (d<3): R6 structure + swizzled epilogue (unchanged R8) ----------------
__global__ __launch_bounds__(256, 4)
void k_final(ushort* __restrict__ hs_h, ushort* __restrict__ hs_l,
             const float* __restrict__ Gq,
             const uint4* __restrict__ wws_h, const uint4* __restrict__ wws_l,
             const float* __restrict__ wb,
             const uint4* __restrict__ trigs_h, const uint4* __restrict__ trigs_l) {
    __shared__ uint4 smem[2560];       // 40 KB unified
    uint4* sH0h = smem;
    uint4* sH0l = smem + 512;
    uint4* sH1h = smem + 1024;
    uint4* sH1l = smem + 1536;
    uint4* sGh  = smem + 2048;
    uint4* sGl  = smem + 2304;
    int blk = blockIdx.x;              // b(8) * y(256) * xq(2), xq fastest
    int xq = blk & 1, y = (blk >> 1) & 255, b = blk >> 9;
    int x0 = xq * 128;
    int t = threadIdx.x;
    int os = t & 63, q = t >> 6;       // Gq staging
    int w = t >> 6, l = t & 63;        // wave w owns o-rows [w*16, w*16+16)
    int lr = l & 15, lq = l >> 4;
    int xs = t & 127, half = t >> 7;   // H staging: x=xs, channels half*16..+15
    f32x4 acc[8];
    {
        int ob = w * 16 + lq * 4;
        f32x4 ini;
        ini[0] = wb[ob]; ini[1] = wb[ob + 1]; ini[2] = wb[ob + 2]; ini[3] = wb[ob + 3];
#pragma unroll
        for (int xt = 0; xt < 8; ++xt) acc[xt] = ini;
    }
    float gv[8];
    {
        const float* gsrc = Gq + ((size_t)(b * 256 + y) * 32 + q * 8) * 64 + os;
#pragma unroll
        for (int kk = 0; kk < 8; ++kk) gv[kk] = gsrc[kk * 64];
    }
    uint4 A0h = wws_h[lq * 64 + w * 16 + lr];
    uint4 A0l = wws_l[lq * 64 + w * 16 + lr];
    uint4 A1h = wws_h[(4 + lq) * 64 + w * 16 + lr];
    uint4 A1l = wws_l[(4 + lq) * 64 + w * 16 + lr];
    size_t hb0 = (size_t)(b * 64 + half * 16) * HW + y * 256 + x0 + xs;
    unsigned hv[16], lv[16];
#pragma unroll
    for (int j = 0; j < 16; ++j) {
        hv[j] = hs_h[hb0 + (size_t)j * HW];
        lv[j] = hs_l[hb0 + (size_t)j * HW];
    }
    {
        uint4 ghq, glq; split_pack8(gv, ghq, glq);
        sGh[q * 64 + os] = ghq; sGl[q * 64 + os] = glq;
    }
#pragma unroll
    for (int c2 = 0; c2 < 2; ++c2) {
        int cell = (half * 2 + c2) * 128 + xs;
        sH0h[cell] = pack8(hv + c2 * 8);
        sH0l[cell] = pack8(lv + c2 * 8);
    }
    unsigned hv1[16], lv1[16];
    size_t hb1 = hb0 + (size_t)32 * HW;
#pragma unroll
    for (int j = 0; j < 16; ++j) {
        hv1[j] = hs_h[hb1 + (size_t)j * HW];
        lv1[j] = hs_l[hb1 + (size_t)j * HW];
    }
    bar_lgkm();
#pragma unroll
    for (int xt = 0; xt < 8; ++xt) {
        bf16x8 Bh = __builtin_bit_cast(bf16x8, sH0h[lq * 128 + xt * 16 + lr]);
        bf16x8 Bl = __builtin_bit_cast(bf16x8, sH0l[lq * 128 + xt * 16 + lr]);
        bf16x8 Ah = __builtin_bit_cast(bf16x8, A0h);
        bf16x8 Al = __builtin_bit_cast(bf16x8, A0l);
        acc[xt] = __builtin_amdgcn_mfma_f32_16x16x32_bf16(Ah, Bh, acc[xt], 0, 0, 0);
        acc[xt] = __builtin_amdgcn_mfma_f32_16x16x32_bf16(Ah, Bl, acc[xt], 0, 0, 0);
        acc[xt] = __builtin_amdgcn_mfma_f32_16x16x32_bf16(Al, Bh, acc[xt], 0, 0, 0);
    }
#pragma unroll
    for (int c2 = 0; c2 < 2; ++c2) {
        int cell = (half * 2 + c2) * 128 + xs;
        sH1h[cell] = pack8(hv1 + c2 * 8);
        sH1l[cell] = pack8(lv1 + c2 * 8);
    }
    bar_lgkm();
#pragma unroll
    for (int xt = 0; xt < 8; ++xt) {
        bf16x8 Bh = __builtin_bit_cast(bf16x8, sH1h[lq * 128 + xt * 16 + lr]);
        bf16x8 Bl = __builtin_bit_cast(bf16x8, sH1l[lq * 128 + xt * 16 + lr]);
        bf16x8 Ah = __builtin_bit_cast(bf16x8, A1h);
        bf16x8 Al = __builtin_bit_cast(bf16x8, A1l);
        acc[xt] = __builtin_amdgcn_mfma_f32_16x16x32_bf16(Ah, Bh, acc[xt], 0, 0, 0);
        acc[xt] = __builtin_amdgcn_mfma_f32_16x16x32_bf16(Ah, Bl, acc[xt], 0, 0, 0);
        acc[xt] = __builtin_amdgcn_mfma_f32_16x16x32_bf16(Al, Bh, acc[xt], 0, 0, 0);
    }
    {
        bf16x8 Ah = __builtin_bit_cast(bf16x8, sGh[lq * 64 + w * 16 + lr]);
        bf16x8 Al = __builtin_bit_cast(bf16x8, sGl[lq * 64 + w * 16 + lr]);
#pragma unroll
        for (int xt = 0; xt < 8; ++xt) {
            bf16x8 Bh = __builtin_bit_cast(bf16x8, trigs_h[lq * 256 + x0 + xt * 16 + lr]);
            bf16x8 Bl = __builtin_bit_cast(bf16x8, trigs_l[lq * 256 + x0 + xt * 16 + lr]);
            acc[xt] = __builtin_amdgcn_mfma_f32_16x16x32_bf16(Ah, Bh, acc[xt], 0, 0, 0);
            acc[xt] = __builtin_amdgcn_mfma_f32_16x16x32_bf16(Ah, Bl, acc[xt], 0, 0, 0);
            acc[xt] = __builtin_amdgcn_mfma_f32_16x16x32_bf16(Al, Bh, acc[xt], 0, 0, 0);
        }
    }
    __syncthreads();
    ushort* eh = (ushort*)smem;
    ushort* el = (ushort*)(smem + 1024);
    int swz = lq * 40;
#pragma unroll
    for (int xt = 0; xt < 8; ++xt)
#pragma unroll
        for (int g = 0; g < 4; ++g) {
            int o = w * 16 + lq * 4 + g;
            float r = fmaxf(acc[xt][g], 0.f);
            ushort hh, ll; split1(r, hh, ll);
            int col = (xt * 16 + lr) ^ swz;
            eh[o * 128 + col] = hh;
            el[o * 128 + col] = ll;
        }
    __syncthreads();
#pragma unroll
    for (int p = 0; p < 4; ++p) {
        int f = t + p * 256;
        int o = f >> 4, seg = f & 15;
        int ko = ((o >> 2) & 3) * 40;
        int cb = (seg * 8) ^ ko;
        size_t base = (size_t)(b * 64 + o) * HW + y * 256 + x0;
        *(uint4*)(hs_h + base + seg * 8) = *(uint4*)(eh + o * 128 + cb);
        *(uint4*)(hs_l + base + seg * 8) = *(uint4*)(el + o * 128 + cb);
    }
}

// ---------------- k_final_fc (d=3): fused fc1/fc2; R22: uint2-packed cell writes
// (0-conflict: 16 disjoint 2-bank windows x 4 lanes = minimum passes) + 4 blk/CU.
__global__ __launch_bounds__(256, 4)
void k_final_fc(const ushort* __restrict__ hs_h, const ushort* __restrict__ hs_l,
                const float* __restrict__ Gq,
                const uint4* __restrict__ wws_h, const uint4* __restrict__ wws_l,
                const float* __restrict__ wb,
                const uint4* __restrict__ trigs_h, const uint4* __restrict__ trigs_l,
                const uint4* __restrict__ w1s_h, const uint4* __restrict__ w1s_l,
                const float* __restrict__ b1, const float* __restrict__ w2,
                const float* __restrict__ b2, float* __restrict__ out) {
    __shared__ uint4 smem[2048];       // 32 KB unified
    uint4* sH0h = smem;
    uint4* sH0l = smem + 512;
    uint4* sH1h = smem + 1024;
    uint4* sH1l = smem + 1536;
    int blk = blockIdx.x;
    int xq = blk & 1, y = (blk >> 1) & 255, b = blk >> 9;
    int x0 = xq * 128;
    int t = threadIdx.x;
    int w = t >> 6, l = t & 63;
    int lr = l & 15, lq = l >> 4;
    int xs = t & 127, half = t >> 7;
    f32x4 acc[8];
    {
        int ob = w * 16 + lq * 4;
        f32x4 ini;
        ini[0] = wb[ob]; ini[1] = wb[ob + 1]; ini[2] = wb[ob + 2]; ini[3] = wb[ob + 3];
#pragma unroll
        for (int xt = 0; xt < 8; ++xt) acc[xt] = ini;
    }
    float gv[8];
    {
        const float* gsrc = Gq + ((size_t)(b * 256 + y) * 32 + lq * 8) * 64 + w * 16 + lr;
#pragma unroll
        for (int kk = 0; kk < 8; ++kk) gv[kk] = gsrc[kk * 64];
    }
    uint4 A0h = wws_h[lq * 64 + w * 16 + lr];
    uint4 A0l = wws_l[lq * 64 + w * 16 + lr];
    uint4 A1h = wws_h[(4 + lq) * 64 + w * 16 + lr];
    uint4 A1l = wws_l[(4 + lq) * 64 + w * 16 + lr];
    size_t hb0 = (size_t)(b * 64 + half * 16) * HW + y * 256 + x0 + xs;
    unsigned hv[16], lv[16];
#pragma unroll
    for (int j = 0; j < 16; ++j) {
        hv[j] = hs_h[hb0 + (size_t)j * HW];
        lv[j] = hs_l[hb0 + (size_t)j * HW];
    }
#pragma unroll
    for (int c2 = 0; c2 < 2; ++c2) {
        int cell = (half * 2 + c2) * 128 + xs;
        sH0h[cell] = pack8(hv + c2 * 8);
        sH0l[cell] = pack8(lv + c2 * 8);
    }
    unsigned hv1[16], lv1[16];
    size_t hb1 = hb0 + (size_t)32 * HW;
#pragma unroll
    for (int j = 0; j < 16; ++j) {
        hv1[j] = hs_h[hb1 + (size_t)j * HW];
        lv1[j] = hs_l[hb1 + (size_t)j * HW];
    }
    bar_lgkm();
#pragma unroll
    for (int xt = 0; xt < 8; ++xt) {
        bf16x8 Bh = __builtin_bit_cast(bf16x8, sH0h[lq * 128 + xt * 16 + lr]);
        bf16x8 Bl = __builtin_bit_cast(bf16x8, sH0l[lq * 128 + xt * 16 + lr]);
        bf16x8 Ah = __builtin_bit_cast(bf16x8, A0h);
        bf16x8 Al = __builtin_bit_cast(bf16x8, A0l);
        acc[xt] = __builtin_amdgcn_mfma_f32_16x16x32_bf16(Ah, Bh, acc[xt], 0, 0, 0);
        acc[xt] = __builtin_amdgcn_mfma_f32_16x16x32_bf16(Ah, Bl, acc[xt], 0, 0, 0);
        acc[xt] = __builtin_amdgcn_mfma_f32_16x16x32_bf16(Al, Bh, acc[xt], 0, 0, 0);
    }
#pragma unroll
    for (int c2 = 0; c2 < 2; ++c2) {
        int cell = (half * 2 + c2) * 128 + xs;
        sH1h[cell] = pack8(hv1 + c2 * 8);
        sH1l[cell] = pack8(lv1 + c2 * 8);
    }
    bar_lgkm();
#pragma unroll
    for (int xt = 0; xt < 8; ++xt) {
        bf16x8 Bh = __builtin_bit_cast(bf16x8, sH1h[lq * 128 + xt * 16 + lr]);
        bf16x8 Bl = __builtin_bit_cast(bf16x8, sH1l[lq * 128 + xt * 16 + lr]);
        bf16x8 Ah = __builtin_bit_cast(bf16x8, A1h);
        bf16x8 Al = __builtin_bit_cast(bf16x8, A1l);
        acc[xt] = __builtin_amdgcn_mfma_f32_16x16x32_bf16(Ah, Bh, acc[xt], 0, 0, 0);
        acc[xt] = __builtin_amdgcn_mfma_f32_16x16x32_bf16(Ah, Bl, acc[xt], 0, 0, 0);
        acc[xt] = __builtin_amdgcn_mfma_f32_16x16x32_bf16(Al, Bh, acc[xt], 0, 0, 0);
    }
    {
        uint4 gh4, gl4; split_pack8(gv, gh4, gl4);
        bf16x8 Ah = __builtin_bit_cast(bf16x8, gh4);
        bf16x8 Al = __builtin_bit_cast(bf16x8, gl4);
#pragma unroll
        for (int xt = 0; xt < 8; ++xt) {
            bf16x8 Bh = __builtin_bit_cast(bf16x8, trigs_h[lq * 256 + x0 + xt * 16 + lr]);
            bf16x8 Bl = __builtin_bit_cast(bf16x8, trigs_l[lq * 256 + x0 + xt * 16 + lr]);
            acc[xt] = __builtin_amdgcn_mfma_f32_16x16x32_bf16(Ah, Bh, acc[xt], 0, 0, 0);
            acc[xt] = __builtin_amdgcn_mfma_f32_16x16x32_bf16(Ah, Bl, acc[xt], 0, 0, 0);
            acc[xt] = __builtin_amdgcn_mfma_f32_16x16x32_bf16(Al, Bh, acc[xt], 0, 0, 0);
        }
    }
    // ---- h_new (relu, split) into LDS cells via uint2-packed writes
    __syncthreads();
    ushort* ch16 = (ushort*)smem;              // hi cells (16 KB)
    ushort* cl16 = (ushort*)(smem + 1024);     // lo cells (16 KB)
    {
        int kcw = w * 2 + (lq >> 1);
        int sb = (lq & 1) * 4;
#pragma unroll
        for (int xt = 0; xt < 8; ++xt) {
            ushort hh[4], ll[4];
#pragma unroll
            for (int g = 0; g < 4; ++g) {
                float r = fmaxf(acc[xt][g], 0.f);
                split1(r, hh[g], ll[g]);
            }
            int ci = (kcw * 128 + xt * 16 + lr) * 8 + sb;
            *(uint2*)(ch16 + ci) = make_uint2(hh[0] | ((unsigned)hh[1] << 16),
                                              hh[2] | ((unsigned)hh[3] << 16));
            *(uint2*)(cl16 + ci) = make_uint2(ll[0] | ((unsigned)ll[1] << 16),
                                              ll[2] | ((unsigned)ll[3] << 16));
        }
    }
    __syncthreads();
    // ---- fc1 GEMM from LDS cells (K=64, 2 phases), A = w1s
    uint4* cells_h = smem;
    uint4* cells_l = smem + 1024;
    int mb = w * 32;
    f32x4 acc2[2][8];
#pragma unroll
    for (int u = 0; u < 2; ++u) {
        int m0 = mb + u * 16 + lq * 4;
        f32x4 ini;
        ini[0] = b1[m0]; ini[1] = b1[m0 + 1]; ini[2] = b1[m0 + 2]; ini[3] = b1[m0 + 3];
#pragma unroll
        for (int xt = 0; xt < 8; ++xt) acc2[u][xt] = ini;
    }
#pragma unroll
    for (int ph = 0; ph < 2; ++ph) {
        bf16x8 Ah[2], Al[2];
#pragma unroll
        for (int u = 0; u < 2; ++u) {
            Ah[u] = __builtin_bit_cast(bf16x8, w1s_h[(ph * 4 + lq) * 128 + mb + u * 16 + lr]);
            Al[u] = __builtin_bit_cast(bf16x8, w1s_l[(ph * 4 + lq) * 128 + mb + u * 16 + lr]);
        }
#pragma unroll
        for (int xt = 0; xt < 8; ++xt) {
            bf16x8 Bh = __builtin_bit_cast(bf16x8, cells_h[(ph * 4 + lq) * 128 + xt * 16 + lr]);
            bf16x8 Bl = __builtin_bit_cast(bf16x8, cells_l[(ph * 4 + lq) * 128 + xt * 16 + lr]);
#pragma unroll
            for (int u = 0; u < 2; ++u) {
                acc2[u][xt] = __builtin_amdgcn_mfma_f32_16x16x32_bf16(Ah[u], Bh, acc2[u][xt], 0, 0, 0);
                acc2[u][xt] = __builtin_amdgcn_mfma_f32_16x16x32_bf16(Ah[u], Bl, acc2[u][xt], 0, 0, 0);
                acc2[u][xt] = __builtin_amdgcn_mfma_f32_16x16x32_bf16(Al[u], Bh, acc2[u][xt], 0, 0, 0);
            }
        }
    }
    // ---- relu + fc2 partials
    float pj[3][8];
#pragma unroll
    for (int j = 0; j < 3; ++j)
#pragma unroll
        for (int xt = 0; xt < 8; ++xt) pj[j][xt] = 0.f;
#pragma unroll
    for (int u = 0; u < 2; ++u)
#pragma unroll
        for (int g = 0; g < 4; ++g) {
            int m = mb + u * 16 + lq * 4 + g;
            float w20 = w2[m], w21 = w2[NMLP + m], w22 = w2[2 * NMLP + m];
#pragma unroll
            for (int xt = 0; xt < 8; ++xt) {
                float r = fmaxf(acc2[u][xt][g], 0.f);
                pj[0][xt] = fmaf(w20, r, pj[0][xt]);
                pj[1][xt] = fmaf(w21, r, pj[1][xt]);
                pj[2][xt] = fmaf(w22, r, pj[2][xt]);
            }
        }
#pragma unroll
    for (int j = 0; j < 3; ++j)
#pragma unroll
        for (int xt = 0; xt < 8; ++xt) {
            float v = pj[j][xt];
            v += __shfl_xor(v, 16);
            v += __shfl_xor(v, 32);
            pj[j][xt] = v;
        }
    __syncthreads();
    float* part = (float*)smem;
    if (lq == 0) {
#pragma unroll
        for (int j = 0; j < 3; ++j)
#pragma unroll
            for (int xt = 0; xt < 8; ++xt)
                part[(w * 3 + j) * 128 + xt * 16 + lr] = pj[j][xt];
    }
    __syncthreads();
#pragma unroll
    for (int r = 0; r < 2; ++r) {
        int idx = t + r * 256;
        if (idx < 384) {
            int j = idx >> 7, xx = idx & 127;
            float s = b2[j];
#pragma unroll
            for (int ww2 = 0; ww2 < 4; ++ww2) s += part[(ww2 * 3 + j) * 128 + xx];
            out[(size_t)(b * 3 + j) * HW + y * 256 + x0 + xx] = s;
        }
    }
}

extern "C" void kernel_launch(void* const* d_in, const int* in_sizes, int n_in,
                              void* d_out, int out_size, void* d_ws, size_t ws_size,
                              hipStream_t stream) {
    const float* x     = (const float*)d_in[0];
    const float* fc0_w = (const float*)d_in[1];
    const float* fc0_b = (const float*)d_in[2];
    const float* swre  = (const float*)d_in[3];
    const float* swim  = (const float*)d_in[4];
    const float* ww    = (const float*)d_in[5];
    const float* wb    = (const float*)d_in[6];
    const float* fc1w  = (const float*)d_in[7];
    const float* fc1b  = (const float*)d_in[8];
    const float* fc2w  = (const float*)d_in[9];
    const float* fc2b  = (const float*)d_in[10];

    float* ws = (float*)d_ws;
    float2* tab     = (float2*)ws;                    // 512 floats
    ushort* hs_h    = (ushort*)(ws + 512);            // 33.5M u16 (67 MB)
    ushort* hs_l    = (ushort*)(ws + 512 + 16777216); // 33.5M u16 (67 MB)
    ushort* T1Fs_h  = (ushort*)(ws + 33554944);       // 4.19M u16 (8.4 MB)
    ushort* T1Fs_l  = (ushort*)(ws + 33554944 + 2097152);
    float2* X       = (float2*)(ws + 37749248);       // 262,144 floats
    float2* Y       = (float2*)(ws + 38011392);       // 262,144 floats
    float*  Gq      = ws + 38273536;                  // 4,194,304
    float*  trig    = ws + 42467840;                  // 8,192
    uint4*  trigs_h = (uint4*)(ws + 42476032);        // 1024 cells
    uint4*  trigs_l = (uint4*)(ws + 42480128);        // 1024 cells
    uint4*  wws_h   = (uint4*)(ws + 42484224);        // 2048 cells
    uint4*  wws_l   = (uint4*)(ws + 42492416);        // 2048 cells
    uint4*  w1s_h   = (uint4*)(ws + 42500608);        // 1024 cells
    uint4*  w1s_l   = (uint4*)(ws + 42504704);        // 1024 cells
    uint4*  ETh     = (uint4*)(ws + 42508800);        // 1024 cells
    uint4*  ETl     = (uint4*)(ws + 42512896);        // 1024 cells
    uint4*  TXh     = (uint4*)(ws + 42516992);        // 1024 cells
    uint4*  TXl     = (uint4*)(ws + 42521088);        // 1024 cells

    k_table<<<dim3(1), dim3(256), 0, stream>>>(tab);
    k_prep0<<<dim3(48), dim3(256), 0, stream>>>(tab, fc1w, ww, trig,
                                                trigs_h, trigs_l, wws_h, wws_l,
                                                w1s_h, w1s_l);
    k_prep_et<<<dim3(8), dim3(256), 0, stream>>>(tab, ETh, ETl, TXh, TXl);
    k_fc0<<<dim3(256), dim3(256), 0, stream>>>(x, fc0_w, fc0_b, hs_h, hs_l);

    for (int d = 0; d < NDEPTH; ++d) {
        k_fwd_y<<<dim3(1024), dim3(256), 0, stream>>>(hs_h, hs_l, ETh, ETl,
                                                      T1Fs_h, T1Fs_l);
        k_fwd_x2<<<dim3(512), dim3(256), 0, stream>>>(T1Fs_h, T1Fs_l, TXh, TXl, X);
        k_mix<<<dim3(256), dim3(256), 0, stream>>>(X, swre + (size_t)d * C * C * 256,
                                                   swim + (size_t)d * C * C * 256, Y);
        k_invy<<<dim3(512), dim3(256), 0, stream>>>(Y, tab, Gq);
        if (d < NDEPTH - 1) {
            k_final<<<dim3(4096), dim3(256), 0, stream>>>(hs_h, hs_l, Gq,
                                                          wws_h + (size_t)d * 512,
                                                          wws_l + (size_t)d * 512,
                                                          wb + d * C, trigs_h, trigs_l);
        } else {
            k_final_fc<<<dim3(4096), dim3(256), 0, stream>>>(hs_h, hs_l, Gq,
                                                             wws_h + (size_t)d * 512,
                                                             wws_l + (size_t)d * 512,
                                                             wb + d * C, trigs_h, trigs_l,
                                                             w1s_h, w1s_l, fc1b, fc2w,
                                                             fc2b, (float*)d_out);
        }
    }
}